// Round 2
// baseline (3383.294 us; speedup 1.0000x reference)
//
#include <hip/hip_runtime.h>
#include <hip/hip_bf16.h>
#include <stdint.h>

// ---------------------------------------------------------------------------
// Performer attention, round 1 (fit workspace ~133 MiB, fuse Q-path).
// B=4, N=4096, C=1024, H=16, D=64, M=256 features.
//
//  K1 gemm_qkv      : x @ w_qkv + b -> Q,K,V bf16 in [bh][n][d]
//  K2 fmap_k_kv     : exact K feature map fused with kv/ksum partials (8 chunks)
//  K3 reduce_kv     : sum partials -> kv[bh][256][64], ksum[bh][256] (f32)
//  K4 contract_fused: Q feature map (scale-invariant form, no sq/rowmax) fused
//                     with (qp.kv)/(qp.ksum+eps) -> attn bf16 (overlays Kh)
//  K5 gemm_out      : attn(bf16) @ w_out + b_out -> d_out (f32)
// ---------------------------------------------------------------------------

#define DN 0.35355339059327379f   // 64^-0.25
#define EPSF 1e-6f
#define INV_SQRT_M 0.0625f        // 1/sqrt(256)

static __device__ __forceinline__ float bflo(uint32_t u) {
    union { uint32_t i; float f; } c; c.i = u << 16; return c.f;
}
static __device__ __forceinline__ float bfhi(uint32_t u) {
    union { uint32_t i; float f; } c; c.i = u & 0xffff0000u; return c.f;
}

// ---------------- K1: qkv projection GEMM (fp32 compute, bf16 out) ----------
__global__ __launch_bounds__(256) void gemm_qkv(const float* __restrict__ A,
                                                const float* __restrict__ B,
                                                const float* __restrict__ bias,
                                                __hip_bfloat16* __restrict__ Qh,
                                                __hip_bfloat16* __restrict__ Kh,
                                                __hip_bfloat16* __restrict__ Vh) {
    const int K = 1024, NN = 3072;
    __shared__ float As[16][68];
    __shared__ float Bs[16][68];
    int t = threadIdx.x;
    int tx = t & 15, ty = t >> 4;
    int rowBase = blockIdx.y * 64;
    int colBase = blockIdx.x * 64;
    float c[4][4] = {};
    for (int k0 = 0; k0 < K; k0 += 16) {
#pragma unroll
        for (int i = 0; i < 4; ++i) {
            int idx = t + i * 256;
            int mr = idx >> 4, kk = idx & 15;
            As[kk][mr] = A[(size_t)(rowBase + mr) * K + k0 + kk];
            int col = idx & 63, kb = idx >> 6;
            Bs[kb][col] = B[(size_t)(k0 + kb) * NN + colBase + col];
        }
        __syncthreads();
#pragma unroll
        for (int kk = 0; kk < 16; ++kk) {
            float4 a4 = *(const float4*)&As[kk][ty * 4];
            float4 b4 = *(const float4*)&Bs[kk][tx * 4];
            float a[4] = {a4.x, a4.y, a4.z, a4.w};
            float b[4] = {b4.x, b4.y, b4.z, b4.w};
#pragma unroll
            for (int i = 0; i < 4; ++i)
#pragma unroll
                for (int j = 0; j < 4; ++j) c[i][j] += a[i] * b[j];
        }
        __syncthreads();
    }
#pragma unroll
    for (int i = 0; i < 4; ++i) {
        int gr = rowBase + ty * 4 + i;
        int b = gr >> 12, n = gr & 4095;
#pragma unroll
        for (int j = 0; j < 4; ++j) {
            int gc = colBase + tx * 4 + j;
            float v = c[i][j] + bias[gc];
            int which = gc >> 10, cc = gc & 1023, h = cc >> 6, dd = cc & 63;
            __hip_bfloat16* dst = (which == 0) ? Qh : ((which == 1) ? Kh : Vh);
            dst[((size_t)(b * 16 + h) * 4096 + n) * 64 + dd] = __float2bfloat16(v);
        }
    }
}

// ------- K2: K feature map (exact) fused with kv/ksum partial sums ---------
__global__ __launch_bounds__(256) void fmap_k_kv(const __hip_bfloat16* __restrict__ Kh,
                                                 const __hip_bfloat16* __restrict__ Vh,
                                                 const float* __restrict__ proj,
                                                 float* __restrict__ kvpart,
                                                 float* __restrict__ kspart) {
    int bh = blockIdx.y, ch = blockIdx.x, h = bh & 15;
    __shared__ __hip_bfloat16 pj[256][70];   // pad 70: conflict-free packed reads
    __shared__ float ks_[4][64];
    __shared__ float vs_[4][64];
    __shared__ float kp_[4][256];
    int t = threadIdx.x, lane = t & 63, w = t >> 6;
    for (int i = t; i < 256 * 64; i += 256) {
        int m = i >> 6, dd = i & 63;
        pj[m][dd] = __float2bfloat16(proj[(size_t)h * 16384 + i]);
    }
    float acc[64];
#pragma unroll
    for (int q = 0; q < 64; ++q) acc[q] = 0.f;
    float ksacc = 0.f;
    int rr = t >> 6, dd = t & 63;
    for (int it = 0; it < 128; ++it) {
        int rbase = ch * 512 + it * 4;
        ks_[rr][dd] = __bfloat162float(Kh[((size_t)bh * 4096 + rbase + rr) * 64 + dd]) * DN;
        vs_[rr][dd] = __bfloat162float(Vh[((size_t)bh * 4096 + rbase + rr) * 64 + dd]);
        __syncthreads();
        float xp[4] = {0.f, 0.f, 0.f, 0.f};
        for (int d2 = 0; d2 < 64; d2 += 2) {
            float2 k2 = *(const float2*)&ks_[w][d2];
#pragma unroll
            for (int j = 0; j < 4; ++j) {
                uint32_t u = *(const uint32_t*)&pj[lane + 64 * j][d2];
                xp[j] += k2.x * bflo(u) + k2.y * bfhi(u);
            }
        }
        float kq = ks_[w][lane];
        float sq = kq * kq;
#pragma unroll
        for (int off = 32; off >= 1; off >>= 1) sq += __shfl_xor(sq, off);
        sq *= 0.5f;
        float val[4]; float vm = -1e30f;
#pragma unroll
        for (int j = 0; j < 4; ++j) { val[j] = xp[j] - sq; vm = fmaxf(vm, val[j]); }
#pragma unroll
        for (int off = 32; off >= 1; off >>= 1) vm = fmaxf(vm, __shfl_xor(vm, off));
#pragma unroll
        for (int j = 0; j < 4; ++j)
            kp_[w][lane + 64 * j] = (__expf(val[j] - vm) + EPSF) * INV_SQRT_M;
        __syncthreads();
#pragma unroll
        for (int r = 0; r < 4; ++r) {
            float s = kp_[r][t];
            ksacc += s;
            const float4* v4 = (const float4*)&vs_[r][0];
#pragma unroll
            for (int q = 0; q < 16; ++q) {
                float4 vv = v4[q];
                acc[4 * q + 0] += s * vv.x; acc[4 * q + 1] += s * vv.y;
                acc[4 * q + 2] += s * vv.z; acc[4 * q + 3] += s * vv.w;
            }
        }
        __syncthreads();
    }
    float4* dst4 = (float4*)(kvpart + ((size_t)(bh * 8 + ch)) * 16384 + (size_t)t * 64);
#pragma unroll
    for (int q = 0; q < 16; ++q)
        dst4[q] = make_float4(acc[4 * q], acc[4 * q + 1], acc[4 * q + 2], acc[4 * q + 3]);
    kspart[(bh * 8 + ch) * 256 + t] = ksacc;
}

// ---------------- K3: reduce 8 partials -> kv, ksum ------------------------
__global__ __launch_bounds__(256) void reduce_kv(const float* __restrict__ kvpart,
                                                 const float* __restrict__ kspart,
                                                 float* __restrict__ kv,
                                                 float* __restrict__ ksum) {
    int gid = blockIdx.x * 256 + threadIdx.x;   // 64*16384 total
    int bh = gid >> 14, md = gid & 16383;
    float s = 0.f;
#pragma unroll
    for (int c2 = 0; c2 < 8; ++c2) s += kvpart[(((size_t)bh * 8 + c2) << 14) + md];
    kv[gid] = s;
    if (gid < 64 * 256) {
        int bh2 = gid >> 8, m = gid & 255;
        float s2 = 0.f;
#pragma unroll
        for (int c2 = 0; c2 < 8; ++c2) s2 += kspart[((bh2 * 8 + c2) << 8) + m];
        ksum[gid] = s2;
    }
}

// ------- K4: fused Q feature map + contraction -----------------------------
// q' uses exp(q.p) directly (row-scale cancels in num/den ratio; eps-induced
// perturbation ~1e-5 relative). Features processed in two halves of 128 so
// proj+kv tiles fit LDS. Per-row num/den accumulate in LDS (owner-exclusive).
__global__ __launch_bounds__(256) void contract_fused(
        const __hip_bfloat16* __restrict__ Qh,
        const float* __restrict__ proj,
        const float* __restrict__ kv,
        const float* __restrict__ ksum,
        __hip_bfloat16* __restrict__ attn) {
    int bh = blockIdx.y, rb = blockIdx.x, h = bh & 15, b = bh >> 4;
    int t = threadIdx.x, lane = t & 63, w = t >> 6;
    __shared__ __hip_bfloat16 qs[64][64];      // 8 KB, pre-scaled by DN
    __shared__ __hip_bfloat16 pj[128][70];     // 17.9 KB
    __shared__ __hip_bfloat16 kvh[128][64];    // 16 KB
    __shared__ __align__(16) float ksh[128];   // 0.5 KB
    __shared__ __align__(16) float ep[4][128]; // 2 KB
    __shared__ float numl[64][64];             // 16 KB
    __shared__ float denl[64];                 // 0.25 KB
    // stage q rows (bf16, pre-scaled) + zero accumulators
    for (int i = t; i < 4096; i += 256) {
        int r = i >> 6, d = i & 63;
        qs[r][d] = __float2bfloat16(
            __bfloat162float(Qh[((size_t)bh * 4096 + rb * 64 + r) * 64 + d]) * DN);
        numl[r][d] = 0.f;
    }
    if (t < 64) denl[t] = 0.f;
    for (int half = 0; half < 2; ++half) {
        __syncthreads();
        for (int i = t; i < 8192; i += 256) {
            int m = i >> 6, d = i & 63;
            pj[m][d] = __float2bfloat16(proj[(size_t)h * 16384 + (half * 128 + m) * 64 + d]);
            kvh[m][d] = __float2bfloat16(kv[((size_t)bh << 14) + (half * 128 + m) * 64 + d]);
        }
        if (t < 128) ksh[t] = ksum[(bh << 8) + half * 128 + t];
        __syncthreads();
        for (int it = 0; it < 16; ++it) {
            int row = it * 4 + w;
            float xp0 = 0.f, xp1 = 0.f;
            for (int d2 = 0; d2 < 64; d2 += 2) {
                uint32_t qu = *(const uint32_t*)&qs[row][d2];   // broadcast
                float qx = bflo(qu), qy = bfhi(qu);
                uint32_t u0 = *(const uint32_t*)&pj[lane][d2];
                uint32_t u1 = *(const uint32_t*)&pj[lane + 64][d2];
                xp0 += qx * bflo(u0) + qy * bfhi(u0);
                xp1 += qx * bflo(u1) + qy * bfhi(u1);
            }
            ep[w][lane]      = (__expf(xp0) + EPSF) * INV_SQRT_M;
            ep[w][lane + 64] = (__expf(xp1) + EPSF) * INV_SQRT_M;
            float an = 0.f, ad = 0.f;
#pragma unroll 4
            for (int m4 = 0; m4 < 32; ++m4) {
                float4 e4 = *(const float4*)&ep[w][m4 * 4];     // broadcast
                float4 s4 = *(const float4*)&ksh[m4 * 4];       // broadcast
                an += e4.x * __bfloat162float(kvh[4 * m4 + 0][lane])
                    + e4.y * __bfloat162float(kvh[4 * m4 + 1][lane])
                    + e4.z * __bfloat162float(kvh[4 * m4 + 2][lane])
                    + e4.w * __bfloat162float(kvh[4 * m4 + 3][lane]);
                ad += e4.x * s4.x + e4.y * s4.y + e4.z * s4.z + e4.w * s4.w;
            }
            numl[row][lane] += an;             // exclusive (row owned by wave w)
            if (lane == 0) denl[row] += ad;
        }
    }
    __syncthreads();
#pragma unroll
    for (int it = 0; it < 16; ++it) {
        int row = it * 4 + w;
        int n = rb * 64 + row;
        attn[((size_t)b * 4096 + n) * 1024 + h * 64 + lane] =
            __float2bfloat16(numl[row][lane] / (denl[row] + EPSF));
    }
}

// ---------------- K5: output GEMM (bf16 A, fp32 B/compute) -----------------
__global__ __launch_bounds__(256) void gemm_out(const __hip_bfloat16* __restrict__ A,
                                                const float* __restrict__ B,
                                                const float* __restrict__ bias,
                                                float* __restrict__ C) {
    const int K = 1024, NN = 1024;
    __shared__ float As[16][68];
    __shared__ float Bs[16][68];
    int t = threadIdx.x;
    int tx = t & 15, ty = t >> 4;
    int rowBase = blockIdx.y * 64;
    int colBase = blockIdx.x * 64;
    float c[4][4] = {};
    for (int k0 = 0; k0 < K; k0 += 16) {
#pragma unroll
        for (int i = 0; i < 4; ++i) {
            int idx = t + i * 256;
            int mr = idx >> 4, kk = idx & 15;
            As[kk][mr] = __bfloat162float(A[(size_t)(rowBase + mr) * K + k0 + kk]);
            int col = idx & 63, kb = idx >> 6;
            Bs[kb][col] = B[(size_t)(k0 + kb) * NN + colBase + col];
        }
        __syncthreads();
#pragma unroll
        for (int kk = 0; kk < 16; ++kk) {
            float4 a4 = *(const float4*)&As[kk][ty * 4];
            float4 b4 = *(const float4*)&Bs[kk][tx * 4];
            float a[4] = {a4.x, a4.y, a4.z, a4.w};
            float b[4] = {b4.x, b4.y, b4.z, b4.w};
#pragma unroll
            for (int i = 0; i < 4; ++i)
#pragma unroll
                for (int j = 0; j < 4; ++j) c[i][j] += a[i] * b[j];
        }
        __syncthreads();
    }
#pragma unroll
    for (int i = 0; i < 4; ++i) {
        int gr = rowBase + ty * 4 + i;
#pragma unroll
        for (int j = 0; j < 4; ++j) {
            int gc = colBase + tx * 4 + j;
            C[(size_t)gr * NN + gc] = c[i][j] + bias[gc];
        }
    }
}

extern "C" void kernel_launch(void* const* d_in, const int* in_sizes, int n_in,
                              void* d_out, int out_size, void* d_ws, size_t ws_size,
                              hipStream_t stream) {
    const float* x      = (const float*)d_in[0];
    const float* w_qkv  = (const float*)d_in[1];
    const float* b_qkv  = (const float*)d_in[2];
    const float* w_out  = (const float*)d_in[3];
    const float* b_out  = (const float*)d_in[4];
    const float* proj   = (const float*)d_in[5];
    float* out = (float*)d_out;

    // workspace layout (bytes), total ~132.6 MiB
    char* w = (char*)d_ws;
    __hip_bfloat16* Qh = (__hip_bfloat16*)(w);                  // 32 MiB
    __hip_bfloat16* Kh = (__hip_bfloat16*)(w + 33554432);       // 32 MiB (-> attn)
    __hip_bfloat16* Vh = (__hip_bfloat16*)(w + 67108864);       // 32 MiB
    float* kvpart = (float*)(w + 100663296);                    // 32 MiB
    float* kspart = (float*)(w + 134217728);                    // 0.5 MiB
    float* kvb    = (float*)(w + 134742016);                    // 4 MiB
    float* ksumb  = (float*)(w + 138936320);                    // 64 KiB
    __hip_bfloat16* attn = Kh;                                  // overlay (Kh dead)

    gemm_qkv<<<dim3(48, 256), 256, 0, stream>>>(x, w_qkv, b_qkv, Qh, Kh, Vh);
    fmap_k_kv<<<dim3(8, 64), 256, 0, stream>>>(Kh, Vh, proj, kvpart, kspart);
    reduce_kv<<<dim3(4096), 256, 0, stream>>>(kvpart, kspart, kvb, ksumb);
    contract_fused<<<dim3(64, 64), 256, 0, stream>>>(Qh, proj, kvb, ksumb, attn);
    gemm_out<<<dim3(16, 256), 256, 0, stream>>>(attn, w_out, b_out, out);
}

// Round 3
// 1677.028 us; speedup vs baseline: 2.0174x; 2.0174x over previous
//
#include <hip/hip_runtime.h>
#include <hip/hip_bf16.h>
#include <stdint.h>

// ---------------------------------------------------------------------------
// Performer attention, round 2: bf16 MFMA for both dense GEMMs (m97 structure).
// B=4, N=4096, C=1024, H=16, D=64, M=256 features.
//
//  K0a conv_x        : x f32 -> bf16 (same layout)
//  K0b convt_w       : w f32 [K][N] -> bf16 [N][K] (transpose so k-contiguous)
//  K1 mfma_gemm_qkv  : xb @ wqT^T + b -> Q,K,V bf16 in [bh][n][d]
//  K2 fmap_k_kv      : exact K feature map fused with kv/ksum partials
//  K3 reduce_kv      : sum partials -> kv[bh][256][64], ksum[bh][256] (f32)
//  K4 contract_fused : Q feature map (scale-invariant) + (qp.kv)/(qp.ksum+eps)
//  K5 mfma_gemm_out  : attn(bf16) @ wOT^T + b_out -> d_out (f32)
// ---------------------------------------------------------------------------

#define DN 0.35355339059327379f   // 64^-0.25
#define EPSF 1e-6f
#define INV_SQRT_M 0.0625f        // 1/sqrt(256)

typedef __attribute__((ext_vector_type(8))) short bf16x8;
typedef __attribute__((ext_vector_type(4))) float f32x4;

static __device__ __forceinline__ float bflo(uint32_t u) {
    union { uint32_t i; float f; } c; c.i = u << 16; return c.f;
}
static __device__ __forceinline__ float bfhi(uint32_t u) {
    union { uint32_t i; float f; } c; c.i = u & 0xffff0000u; return c.f;
}
static __device__ __forceinline__ short f2bf(float f) {
    __hip_bfloat16 h = __float2bfloat16(f);
    return *(short*)&h;
}
static __device__ __forceinline__ void gload16(const void* g, void* l) {
    __builtin_amdgcn_global_load_lds(
        (const __attribute__((address_space(1))) void*)g,
        (__attribute__((address_space(3))) void*)l,
        16, 0, 0);
}

// ---------------- K0a: x f32 -> bf16 ---------------------------------------
__global__ __launch_bounds__(256) void conv_x(const float* __restrict__ X,
                                              short* __restrict__ Xb) {
    int i = blockIdx.x * 256 + threadIdx.x;      // one float4 each
    float4 v = ((const float4*)X)[i];
    short4 o;
    o.x = f2bf(v.x); o.y = f2bf(v.y); o.z = f2bf(v.z); o.w = f2bf(v.w);
    ((short4*)Xb)[i] = o;
}

// ---------------- K0b: W [K][NN] f32 -> WT [NN][K] bf16 --------------------
__global__ __launch_bounds__(256) void convt_w(const float* __restrict__ W,
                                               short* __restrict__ WT,
                                               int K, int NN) {
    __shared__ short tile[64][66];
    int t = threadIdx.x;
    int k0 = blockIdx.y * 64, n0 = blockIdx.x * 64;
    for (int i = t; i < 4096; i += 256) {
        int r = i >> 6, c = i & 63;              // r: k, c: n
        tile[r][c] = f2bf(W[(size_t)(k0 + r) * NN + n0 + c]);
    }
    __syncthreads();
    for (int i = t; i < 4096; i += 256) {
        int r = i >> 6, c = i & 63;              // r: n, c: k
        WT[(size_t)(n0 + r) * K + k0 + c] = tile[c][r];
    }
}

// ---------------- K1: MFMA GEMM -> Q,K,V bf16 ------------------------------
// A [16384][1024] bf16 row-major, BT [3072][1024] bf16 (= B^T), both
// k-contiguous. 128x128 tile, BK=32, 4 waves (2x2), 16x16x32 bf16 MFMA.
__global__ __launch_bounds__(256) void mfma_gemm_qkv(const short* __restrict__ A,
                                                     const short* __restrict__ BT,
                                                     const float* __restrict__ bias,
                                                     short* __restrict__ Qh,
                                                     short* __restrict__ Kh,
                                                     short* __restrict__ Vh) {
    const int K = 1024;
    __shared__ short lA[128 * 32];
    __shared__ short lB[128 * 32];
    int t = threadIdx.x, lane = t & 63, w = t >> 6;
    int wm = w >> 1, wn = w & 1;
    int rowBase = blockIdx.y * 128, colBase = blockIdx.x * 128;

    // staging: each wave fills rows [w*32, w*32+32) of lA and lB.
    // wave-load i covers 16 rows; lane l -> row +(l>>2), bytes (l&3)*16.
    int rs = (lane >> 2), cb = (lane & 3) * 16;
    const char* gA0 = (const char*)(A + (size_t)(rowBase + w * 32 + rs) * K) + cb;
    const char* gA1 = (const char*)(A + (size_t)(rowBase + w * 32 + 16 + rs) * K) + cb;
    const char* gB0 = (const char*)(BT + (size_t)(colBase + w * 32 + rs) * K) + cb;
    const char* gB1 = (const char*)(BT + (size_t)(colBase + w * 32 + 16 + rs) * K) + cb;
    char* dA0 = (char*)lA + (w * 32) * 64;
    char* dA1 = (char*)lA + (w * 32 + 16) * 64;
    char* dB0 = (char*)lB + (w * 32) * 64;
    char* dB1 = (char*)lB + (w * 32 + 16) * 64;

    // fragment read byte-offsets (constant over K-loop)
    int offA[4], offB[4];
#pragma unroll
    for (int m = 0; m < 4; ++m) {
        offA[m] = (wm * 64 + m * 16 + (lane & 15)) * 64 + (lane >> 4) * 16;
        offB[m] = (wn * 64 + m * 16 + (lane & 15)) * 64 + (lane >> 4) * 16;
    }

    f32x4 acc[4][4];
#pragma unroll
    for (int m = 0; m < 4; ++m)
#pragma unroll
        for (int n = 0; n < 4; ++n) acc[m][n] = (f32x4){0.f, 0.f, 0.f, 0.f};

    for (int k0 = 0; k0 < K; k0 += 32) {
        size_t kb = (size_t)k0 * 2;              // byte advance along k
        gload16(gA0 + kb, dA0);
        gload16(gA1 + kb, dA1);
        gload16(gB0 + kb, dB0);
        gload16(gB1 + kb, dB1);
        __syncthreads();
        bf16x8 af[4], bfr[4];
#pragma unroll
        for (int m = 0; m < 4; ++m) af[m] = *(const bf16x8*)((const char*)lA + offA[m]);
#pragma unroll
        for (int n = 0; n < 4; ++n) bfr[n] = *(const bf16x8*)((const char*)lB + offB[n]);
#pragma unroll
        for (int m = 0; m < 4; ++m)
#pragma unroll
            for (int n = 0; n < 4; ++n)
                acc[m][n] = __builtin_amdgcn_mfma_f32_16x16x32_bf16(af[m], bfr[n], acc[m][n], 0, 0, 0);
        __syncthreads();
    }

    // epilogue: bias + scatter to Q/K/V [bh][n][d] bf16
    float bcol[4];
#pragma unroll
    for (int n = 0; n < 4; ++n)
        bcol[n] = bias[colBase + wn * 64 + n * 16 + (lane & 15)];
#pragma unroll
    for (int n = 0; n < 4; ++n) {
        int gc = colBase + wn * 64 + n * 16 + (lane & 15);
        int which = gc >> 10, cc = gc & 1023, h = cc >> 6, dd = cc & 63;
        short* dst = (which == 0) ? Qh : ((which == 1) ? Kh : Vh);
#pragma unroll
        for (int m = 0; m < 4; ++m) {
#pragma unroll
            for (int j = 0; j < 4; ++j) {
                int gr = rowBase + wm * 64 + m * 16 + (lane >> 4) * 4 + j;
                int b = gr >> 12, nn = gr & 4095;
                dst[((size_t)(b * 16 + h) * 4096 + nn) * 64 + dd] =
                    f2bf(acc[m][n][j] + bcol[n]);
            }
        }
    }
}

// ---------------- K5: MFMA GEMM -> d_out f32 -------------------------------
__global__ __launch_bounds__(256) void mfma_gemm_out(const short* __restrict__ A,
                                                     const short* __restrict__ BT,
                                                     const float* __restrict__ bias,
                                                     float* __restrict__ C) {
    const int K = 1024, NN = 1024;
    __shared__ short lA[128 * 32];
    __shared__ short lB[128 * 32];
    int t = threadIdx.x, lane = t & 63, w = t >> 6;
    int wm = w >> 1, wn = w & 1;
    int rowBase = blockIdx.y * 128, colBase = blockIdx.x * 128;

    int rs = (lane >> 2), cb = (lane & 3) * 16;
    const char* gA0 = (const char*)(A + (size_t)(rowBase + w * 32 + rs) * K) + cb;
    const char* gA1 = (const char*)(A + (size_t)(rowBase + w * 32 + 16 + rs) * K) + cb;
    const char* gB0 = (const char*)(BT + (size_t)(colBase + w * 32 + rs) * K) + cb;
    const char* gB1 = (const char*)(BT + (size_t)(colBase + w * 32 + 16 + rs) * K) + cb;
    char* dA0 = (char*)lA + (w * 32) * 64;
    char* dA1 = (char*)lA + (w * 32 + 16) * 64;
    char* dB0 = (char*)lB + (w * 32) * 64;
    char* dB1 = (char*)lB + (w * 32 + 16) * 64;

    int offA[4], offB[4];
#pragma unroll
    for (int m = 0; m < 4; ++m) {
        offA[m] = (wm * 64 + m * 16 + (lane & 15)) * 64 + (lane >> 4) * 16;
        offB[m] = (wn * 64 + m * 16 + (lane & 15)) * 64 + (lane >> 4) * 16;
    }

    f32x4 acc[4][4];
#pragma unroll
    for (int m = 0; m < 4; ++m)
#pragma unroll
        for (int n = 0; n < 4; ++n) acc[m][n] = (f32x4){0.f, 0.f, 0.f, 0.f};

    for (int k0 = 0; k0 < K; k0 += 32) {
        size_t kb = (size_t)k0 * 2;
        gload16(gA0 + kb, dA0);
        gload16(gA1 + kb, dA1);
        gload16(gB0 + kb, dB0);
        gload16(gB1 + kb, dB1);
        __syncthreads();
        bf16x8 af[4], bfr[4];
#pragma unroll
        for (int m = 0; m < 4; ++m) af[m] = *(const bf16x8*)((const char*)lA + offA[m]);
#pragma unroll
        for (int n = 0; n < 4; ++n) bfr[n] = *(const bf16x8*)((const char*)lB + offB[n]);
#pragma unroll
        for (int m = 0; m < 4; ++m)
#pragma unroll
            for (int n = 0; n < 4; ++n)
                acc[m][n] = __builtin_amdgcn_mfma_f32_16x16x32_bf16(af[m], bfr[n], acc[m][n], 0, 0, 0);
        __syncthreads();
    }

    float bcol[4];
#pragma unroll
    for (int n = 0; n < 4; ++n)
        bcol[n] = bias[colBase + wn * 64 + n * 16 + (lane & 15)];
#pragma unroll
    for (int m = 0; m < 4; ++m) {
#pragma unroll
        for (int j = 0; j < 4; ++j) {
            int gr = rowBase + wm * 64 + m * 16 + (lane >> 4) * 4 + j;
#pragma unroll
            for (int n = 0; n < 4; ++n) {
                int gc = colBase + wn * 64 + n * 16 + (lane & 15);
                C[(size_t)gr * NN + gc] = acc[m][n][j] + bcol[n];
            }
        }
    }
}

// ------- K2: K feature map (exact) fused with kv/ksum partial sums ---------
__global__ __launch_bounds__(256) void fmap_k_kv(const __hip_bfloat16* __restrict__ Kh,
                                                 const __hip_bfloat16* __restrict__ Vh,
                                                 const float* __restrict__ proj,
                                                 float* __restrict__ kvpart,
                                                 float* __restrict__ kspart) {
    int bh = blockIdx.y, ch = blockIdx.x, h = bh & 15;
    __shared__ __hip_bfloat16 pj[256][70];   // pad 70: conflict-free packed reads
    __shared__ float ks_[4][64];
    __shared__ float vs_[4][64];
    __shared__ float kp_[4][256];
    int t = threadIdx.x, lane = t & 63, w = t >> 6;
    for (int i = t; i < 256 * 64; i += 256) {
        int m = i >> 6, dd = i & 63;
        pj[m][dd] = __float2bfloat16(proj[(size_t)h * 16384 + i]);
    }
    float acc[64];
#pragma unroll
    for (int q = 0; q < 64; ++q) acc[q] = 0.f;
    float ksacc = 0.f;
    int rr = t >> 6, dd = t & 63;
    for (int it = 0; it < 128; ++it) {
        int rbase = ch * 512 + it * 4;
        ks_[rr][dd] = __bfloat162float(Kh[((size_t)bh * 4096 + rbase + rr) * 64 + dd]) * DN;
        vs_[rr][dd] = __bfloat162float(Vh[((size_t)bh * 4096 + rbase + rr) * 64 + dd]);
        __syncthreads();
        float xp[4] = {0.f, 0.f, 0.f, 0.f};
        for (int d2 = 0; d2 < 64; d2 += 2) {
            float2 k2 = *(const float2*)&ks_[w][d2];
#pragma unroll
            for (int j = 0; j < 4; ++j) {
                uint32_t u = *(const uint32_t*)&pj[lane + 64 * j][d2];
                xp[j] += k2.x * bflo(u) + k2.y * bfhi(u);
            }
        }
        float kq = ks_[w][lane];
        float sq = kq * kq;
#pragma unroll
        for (int off = 32; off >= 1; off >>= 1) sq += __shfl_xor(sq, off);
        sq *= 0.5f;
        float val[4]; float vm = -1e30f;
#pragma unroll
        for (int j = 0; j < 4; ++j) { val[j] = xp[j] - sq; vm = fmaxf(vm, val[j]); }
#pragma unroll
        for (int off = 32; off >= 1; off >>= 1) vm = fmaxf(vm, __shfl_xor(vm, off));
#pragma unroll
        for (int j = 0; j < 4; ++j)
            kp_[w][lane + 64 * j] = (__expf(val[j] - vm) + EPSF) * INV_SQRT_M;
        __syncthreads();
#pragma unroll
        for (int r = 0; r < 4; ++r) {
            float s = kp_[r][t];
            ksacc += s;
            const float4* v4 = (const float4*)&vs_[r][0];
#pragma unroll
            for (int q = 0; q < 16; ++q) {
                float4 vv = v4[q];
                acc[4 * q + 0] += s * vv.x; acc[4 * q + 1] += s * vv.y;
                acc[4 * q + 2] += s * vv.z; acc[4 * q + 3] += s * vv.w;
            }
        }
        __syncthreads();
    }
    float4* dst4 = (float4*)(kvpart + ((size_t)(bh * 8 + ch)) * 16384 + (size_t)t * 64);
#pragma unroll
    for (int q = 0; q < 16; ++q)
        dst4[q] = make_float4(acc[4 * q], acc[4 * q + 1], acc[4 * q + 2], acc[4 * q + 3]);
    kspart[(bh * 8 + ch) * 256 + t] = ksacc;
}

// ---------------- K3: reduce 8 partials -> kv, ksum ------------------------
__global__ __launch_bounds__(256) void reduce_kv(const float* __restrict__ kvpart,
                                                 const float* __restrict__ kspart,
                                                 float* __restrict__ kv,
                                                 float* __restrict__ ksum) {
    int gid = blockIdx.x * 256 + threadIdx.x;   // 64*16384 total
    int bh = gid >> 14, md = gid & 16383;
    float s = 0.f;
#pragma unroll
    for (int c2 = 0; c2 < 8; ++c2) s += kvpart[(((size_t)bh * 8 + c2) << 14) + md];
    kv[gid] = s;
    if (gid < 64 * 256) {
        int bh2 = gid >> 8, m = gid & 255;
        float s2 = 0.f;
#pragma unroll
        for (int c2 = 0; c2 < 8; ++c2) s2 += kspart[((bh2 * 8 + c2) << 8) + m];
        ksum[gid] = s2;
    }
}

// ------- K4: fused Q feature map + contraction -----------------------------
__global__ __launch_bounds__(256) void contract_fused(
        const __hip_bfloat16* __restrict__ Qh,
        const float* __restrict__ proj,
        const float* __restrict__ kv,
        const float* __restrict__ ksum,
        __hip_bfloat16* __restrict__ attn) {
    int bh = blockIdx.y, rb = blockIdx.x, h = bh & 15, b = bh >> 4;
    int t = threadIdx.x, lane = t & 63, w = t >> 6;
    __shared__ __hip_bfloat16 qs[64][64];      // 8 KB, pre-scaled by DN
    __shared__ __hip_bfloat16 pj[128][70];     // 17.9 KB
    __shared__ __hip_bfloat16 kvh[128][64];    // 16 KB
    __shared__ __align__(16) float ksh[128];   // 0.5 KB
    __shared__ __align__(16) float ep[4][128]; // 2 KB
    __shared__ float numl[64][64];             // 16 KB
    __shared__ float denl[64];                 // 0.25 KB
    for (int i = t; i < 4096; i += 256) {
        int r = i >> 6, d = i & 63;
        qs[r][d] = __float2bfloat16(
            __bfloat162float(Qh[((size_t)bh * 4096 + rb * 64 + r) * 64 + d]) * DN);
        numl[r][d] = 0.f;
    }
    if (t < 64) denl[t] = 0.f;
    for (int half = 0; half < 2; ++half) {
        __syncthreads();
        for (int i = t; i < 8192; i += 256) {
            int m = i >> 6, d = i & 63;
            pj[m][d] = __float2bfloat16(proj[(size_t)h * 16384 + (half * 128 + m) * 64 + d]);
            kvh[m][d] = __float2bfloat16(kv[((size_t)bh << 14) + (half * 128 + m) * 64 + d]);
        }
        if (t < 128) ksh[t] = ksum[(bh << 8) + half * 128 + t];
        __syncthreads();
        for (int it = 0; it < 16; ++it) {
            int row = it * 4 + w;
            float xp0 = 0.f, xp1 = 0.f;
            for (int d2 = 0; d2 < 64; d2 += 2) {
                uint32_t qu = *(const uint32_t*)&qs[row][d2];   // broadcast
                float qx = bflo(qu), qy = bfhi(qu);
                uint32_t u0 = *(const uint32_t*)&pj[lane][d2];
                uint32_t u1 = *(const uint32_t*)&pj[lane + 64][d2];
                xp0 += qx * bflo(u0) + qy * bfhi(u0);
                xp1 += qx * bflo(u1) + qy * bfhi(u1);
            }
            ep[w][lane]      = (__expf(xp0) + EPSF) * INV_SQRT_M;
            ep[w][lane + 64] = (__expf(xp1) + EPSF) * INV_SQRT_M;
            float an = 0.f, ad = 0.f;
#pragma unroll 4
            for (int m4 = 0; m4 < 32; ++m4) {
                float4 e4 = *(const float4*)&ep[w][m4 * 4];     // broadcast
                float4 s4 = *(const float4*)&ksh[m4 * 4];       // broadcast
                an += e4.x * __bfloat162float(kvh[4 * m4 + 0][lane])
                    + e4.y * __bfloat162float(kvh[4 * m4 + 1][lane])
                    + e4.z * __bfloat162float(kvh[4 * m4 + 2][lane])
                    + e4.w * __bfloat162float(kvh[4 * m4 + 3][lane]);
                ad += e4.x * s4.x + e4.y * s4.y + e4.z * s4.z + e4.w * s4.w;
            }
            numl[row][lane] += an;             // exclusive (row owned by wave w)
            if (lane == 0) denl[row] += ad;
        }
    }
    __syncthreads();
#pragma unroll
    for (int it = 0; it < 16; ++it) {
        int row = it * 4 + w;
        int n = rb * 64 + row;
        attn[((size_t)b * 4096 + n) * 1024 + h * 64 + lane] =
            __float2bfloat16(numl[row][lane] / (denl[row] + EPSF));
    }
}

extern "C" void kernel_launch(void* const* d_in, const int* in_sizes, int n_in,
                              void* d_out, int out_size, void* d_ws, size_t ws_size,
                              hipStream_t stream) {
    const float* x      = (const float*)d_in[0];
    const float* w_qkv  = (const float*)d_in[1];
    const float* b_qkv  = (const float*)d_in[2];
    const float* w_out  = (const float*)d_in[3];
    const float* b_out  = (const float*)d_in[4];
    const float* proj   = (const float*)d_in[5];
    float* out = (float*)d_out;

    // workspace layout (bytes), total ~140.6 MiB
    char* w = (char*)d_ws;
    short* xb     = (short*)(w);                        // 32 MiB [0,32M) -> kvpart after K1
    short* wqT    = (short*)(w + 33554432);             // 6 MiB
    short* wOT    = (short*)(w + 39845888);             // 2 MiB
    short* Qh     = (short*)(w + 41943040);             // 32 MiB
    short* Kh     = (short*)(w + 75497472);             // 32 MiB (-> attn overlay)
    short* Vh     = (short*)(w + 109051904);            // 32 MiB
    float* kvpart = (float*)(w);                        // overlay (xb dead after K1)
    float* kspart = (float*)(w + 142606336);            // 512 KiB
    float* kvb    = (float*)(w + 143130624);            // 4 MiB
    float* ksumb  = (float*)(w + 147324928);            // 64 KiB
    short* attn   = Kh;                                 // overlay (Kh dead after K2)

    conv_x<<<dim3(16384), 256, 0, stream>>>(x, xb);
    convt_w<<<dim3(48, 16), 256, 0, stream>>>(w_qkv, wqT, 1024, 3072);
    convt_w<<<dim3(16, 16), 256, 0, stream>>>(w_out, wOT, 1024, 1024);
    mfma_gemm_qkv<<<dim3(24, 128), 256, 0, stream>>>(xb, wqT, b_qkv, Qh, Kh, Vh);
    fmap_k_kv<<<dim3(8, 64), 256, 0, stream>>>((const __hip_bfloat16*)Kh,
                                               (const __hip_bfloat16*)Vh, proj,
                                               kvpart, kspart);
    reduce_kv<<<dim3(4096), 256, 0, stream>>>(kvpart, kspart, kvb, ksumb);
    contract_fused<<<dim3(64, 64), 256, 0, stream>>>((const __hip_bfloat16*)Qh, proj,
                                                     kvb, ksumb,
                                                     (__hip_bfloat16*)attn);
    mfma_gemm_out<<<dim3(8, 128), 256, 0, stream>>>(attn, wOT, b_out, out);
}

// Round 4
// 955.588 us; speedup vs baseline: 3.5405x; 1.7550x over previous
//
#include <hip/hip_runtime.h>
#include <hip/hip_bf16.h>
#include <stdint.h>

// ---------------------------------------------------------------------------
// Performer attention, round 3: contract kernel -> MFMA (2-stage, swizzled LDS).
// B=4, N=4096, C=1024, H=16, D=64, M=256 features.
//
//  K0a conv_x        : x f32 -> bf16
//  K0b convt_w       : w f32 [K][N] -> bf16 [N][K]
//  K0c conv_proj     : proj f32 -> bf16 [h][m][d^((m&7)<<3)] (pre-swizzled)
//  K1 mfma_gemm_qkv  : xb @ wqT^T + b -> Q(pre-swizzled,*DN),K,V bf16 [bh][n][d]
//  K2 fmap_k_kv      : exact K feature map fused with kv/ksum partials
//  K3 reduce_kv      : partials -> kvT_sw bf16 [bh][80][256] (pre-swizzled,
//                      row64=ksum, rows 65-79 = 0)
//  K4 contract_mfma  : S^T=mfma(proj,q); P=exp; out=mfma(P, kvT) incl den frag
//  K5 mfma_gemm_out  : attn(bf16) @ wOT^T + b_out -> d_out (f32)
// ---------------------------------------------------------------------------

#define DN 0.35355339059327379f   // 64^-0.25
#define EPSF 1e-6f
#define INV_SQRT_M 0.0625f        // 1/sqrt(256)

typedef __attribute__((ext_vector_type(8))) short bf16x8;
typedef __attribute__((ext_vector_type(4))) float f32x4;

static __device__ __forceinline__ float bflo(uint32_t u) {
    union { uint32_t i; float f; } c; c.i = u << 16; return c.f;
}
static __device__ __forceinline__ float bfhi(uint32_t u) {
    union { uint32_t i; float f; } c; c.i = u & 0xffff0000u; return c.f;
}
static __device__ __forceinline__ short f2bf(float f) {
    __hip_bfloat16 h = __float2bfloat16(f);
    return *(short*)&h;
}
static __device__ __forceinline__ void gload16(const void* g, void* l) {
    __builtin_amdgcn_global_load_lds(
        (const __attribute__((address_space(1))) void*)g,
        (__attribute__((address_space(3))) void*)l,
        16, 0, 0);
}

// ---------------- K0a: x f32 -> bf16 ---------------------------------------
__global__ __launch_bounds__(256) void conv_x(const float* __restrict__ X,
                                              short* __restrict__ Xb) {
    int i = blockIdx.x * 256 + threadIdx.x;
    float4 v = ((const float4*)X)[i];
    short4 o;
    o.x = f2bf(v.x); o.y = f2bf(v.y); o.z = f2bf(v.z); o.w = f2bf(v.w);
    ((short4*)Xb)[i] = o;
}

// ---------------- K0b: W [K][NN] f32 -> WT [NN][K] bf16 --------------------
__global__ __launch_bounds__(256) void convt_w(const float* __restrict__ W,
                                               short* __restrict__ WT,
                                               int K, int NN) {
    __shared__ short tile[64][66];
    int t = threadIdx.x;
    int k0 = blockIdx.y * 64, n0 = blockIdx.x * 64;
    for (int i = t; i < 4096; i += 256) {
        int r = i >> 6, c = i & 63;
        tile[r][c] = f2bf(W[(size_t)(k0 + r) * NN + n0 + c]);
    }
    __syncthreads();
    for (int i = t; i < 4096; i += 256) {
        int r = i >> 6, c = i & 63;
        WT[(size_t)(n0 + r) * K + k0 + c] = tile[c][r];
    }
}

// ---------------- K0c: proj f32 -> bf16 pre-swizzled -----------------------
__global__ __launch_bounds__(256) void conv_proj(const float* __restrict__ proj,
                                                 short* __restrict__ pjb) {
    int e = blockIdx.x * 256 + threadIdx.x;    // 262144 total
    int m = (e >> 6) & 255, d = e & 63;
    int base = e & ~63;
    pjb[base + (d ^ ((m & 7) << 3))] = f2bf(proj[e]);
}

// ---------------- K1: MFMA GEMM -> Q,K,V bf16 ------------------------------
__global__ __launch_bounds__(256) void mfma_gemm_qkv(const short* __restrict__ A,
                                                     const short* __restrict__ BT,
                                                     const float* __restrict__ bias,
                                                     short* __restrict__ Qh,
                                                     short* __restrict__ Kh,
                                                     short* __restrict__ Vh) {
    const int K = 1024;
    __shared__ short lA[128 * 32];
    __shared__ short lB[128 * 32];
    int t = threadIdx.x, lane = t & 63, w = t >> 6;
    int wm = w >> 1, wn = w & 1;
    int rowBase = blockIdx.y * 128, colBase = blockIdx.x * 128;

    int rs = (lane >> 2), cb = (lane & 3) * 16;
    const char* gA0 = (const char*)(A + (size_t)(rowBase + w * 32 + rs) * K) + cb;
    const char* gA1 = (const char*)(A + (size_t)(rowBase + w * 32 + 16 + rs) * K) + cb;
    const char* gB0 = (const char*)(BT + (size_t)(colBase + w * 32 + rs) * K) + cb;
    const char* gB1 = (const char*)(BT + (size_t)(colBase + w * 32 + 16 + rs) * K) + cb;
    char* dA0 = (char*)lA + (w * 32) * 64;
    char* dA1 = (char*)lA + (w * 32 + 16) * 64;
    char* dB0 = (char*)lB + (w * 32) * 64;
    char* dB1 = (char*)lB + (w * 32 + 16) * 64;

    int offA[4], offB[4];
#pragma unroll
    for (int m = 0; m < 4; ++m) {
        offA[m] = (wm * 64 + m * 16 + (lane & 15)) * 64 + (lane >> 4) * 16;
        offB[m] = (wn * 64 + m * 16 + (lane & 15)) * 64 + (lane >> 4) * 16;
    }

    f32x4 acc[4][4];
#pragma unroll
    for (int m = 0; m < 4; ++m)
#pragma unroll
        for (int n = 0; n < 4; ++n) acc[m][n] = (f32x4){0.f, 0.f, 0.f, 0.f};

    for (int k0 = 0; k0 < K; k0 += 32) {
        size_t kb = (size_t)k0 * 2;
        gload16(gA0 + kb, dA0);
        gload16(gA1 + kb, dA1);
        gload16(gB0 + kb, dB0);
        gload16(gB1 + kb, dB1);
        __syncthreads();
        bf16x8 af[4], bfr[4];
#pragma unroll
        for (int m = 0; m < 4; ++m) af[m] = *(const bf16x8*)((const char*)lA + offA[m]);
#pragma unroll
        for (int n = 0; n < 4; ++n) bfr[n] = *(const bf16x8*)((const char*)lB + offB[n]);
#pragma unroll
        for (int m = 0; m < 4; ++m)
#pragma unroll
            for (int n = 0; n < 4; ++n)
                acc[m][n] = __builtin_amdgcn_mfma_f32_16x16x32_bf16(af[m], bfr[n], acc[m][n], 0, 0, 0);
        __syncthreads();
    }

    float bcol[4];
#pragma unroll
    for (int n = 0; n < 4; ++n)
        bcol[n] = bias[colBase + wn * 64 + n * 16 + (lane & 15)];
#pragma unroll
    for (int n = 0; n < 4; ++n) {
        int gc = colBase + wn * 64 + n * 16 + (lane & 15);
        int which = gc >> 10, cc = gc & 1023, h = cc >> 6, dd = cc & 63;
        short* dst = (which == 0) ? Qh : ((which == 1) ? Kh : Vh);
#pragma unroll
        for (int m = 0; m < 4; ++m) {
#pragma unroll
            for (int j = 0; j < 4; ++j) {
                int gr = rowBase + wm * 64 + m * 16 + (lane >> 4) * 4 + j;
                int b = gr >> 12, nn = gr & 4095;
                float v = acc[m][n][j] + bcol[n];
                if (which == 0) {
                    // Q: prescale by DN, pre-swizzle d for contract LDS reads
                    int dsw = dd ^ ((nn & 7) << 3);
                    dst[((size_t)(b * 16 + h) * 4096 + nn) * 64 + dsw] = f2bf(v * DN);
                } else {
                    dst[((size_t)(b * 16 + h) * 4096 + nn) * 64 + dd] = f2bf(v);
                }
            }
        }
    }
}

// ---------------- K5: MFMA GEMM -> d_out f32 -------------------------------
__global__ __launch_bounds__(256) void mfma_gemm_out(const short* __restrict__ A,
                                                     const short* __restrict__ BT,
                                                     const float* __restrict__ bias,
                                                     float* __restrict__ C) {
    const int K = 1024, NN = 1024;
    __shared__ short lA[128 * 32];
    __shared__ short lB[128 * 32];
    int t = threadIdx.x, lane = t & 63, w = t >> 6;
    int wm = w >> 1, wn = w & 1;
    int rowBase = blockIdx.y * 128, colBase = blockIdx.x * 128;

    int rs = (lane >> 2), cb = (lane & 3) * 16;
    const char* gA0 = (const char*)(A + (size_t)(rowBase + w * 32 + rs) * K) + cb;
    const char* gA1 = (const char*)(A + (size_t)(rowBase + w * 32 + 16 + rs) * K) + cb;
    const char* gB0 = (const char*)(BT + (size_t)(colBase + w * 32 + rs) * K) + cb;
    const char* gB1 = (const char*)(BT + (size_t)(colBase + w * 32 + 16 + rs) * K) + cb;
    char* dA0 = (char*)lA + (w * 32) * 64;
    char* dA1 = (char*)lA + (w * 32 + 16) * 64;
    char* dB0 = (char*)lB + (w * 32) * 64;
    char* dB1 = (char*)lB + (w * 32 + 16) * 64;

    int offA[4], offB[4];
#pragma unroll
    for (int m = 0; m < 4; ++m) {
        offA[m] = (wm * 64 + m * 16 + (lane & 15)) * 64 + (lane >> 4) * 16;
        offB[m] = (wn * 64 + m * 16 + (lane & 15)) * 64 + (lane >> 4) * 16;
    }

    f32x4 acc[4][4];
#pragma unroll
    for (int m = 0; m < 4; ++m)
#pragma unroll
        for (int n = 0; n < 4; ++n) acc[m][n] = (f32x4){0.f, 0.f, 0.f, 0.f};

    for (int k0 = 0; k0 < K; k0 += 32) {
        size_t kb = (size_t)k0 * 2;
        gload16(gA0 + kb, dA0);
        gload16(gA1 + kb, dA1);
        gload16(gB0 + kb, dB0);
        gload16(gB1 + kb, dB1);
        __syncthreads();
        bf16x8 af[4], bfr[4];
#pragma unroll
        for (int m = 0; m < 4; ++m) af[m] = *(const bf16x8*)((const char*)lA + offA[m]);
#pragma unroll
        for (int n = 0; n < 4; ++n) bfr[n] = *(const bf16x8*)((const char*)lB + offB[n]);
#pragma unroll
        for (int m = 0; m < 4; ++m)
#pragma unroll
            for (int n = 0; n < 4; ++n)
                acc[m][n] = __builtin_amdgcn_mfma_f32_16x16x32_bf16(af[m], bfr[n], acc[m][n], 0, 0, 0);
        __syncthreads();
    }

    float bcol[4];
#pragma unroll
    for (int n = 0; n < 4; ++n)
        bcol[n] = bias[colBase + wn * 64 + n * 16 + (lane & 15)];
#pragma unroll
    for (int m = 0; m < 4; ++m) {
#pragma unroll
        for (int j = 0; j < 4; ++j) {
            int gr = rowBase + wm * 64 + m * 16 + (lane >> 4) * 4 + j;
#pragma unroll
            for (int n = 0; n < 4; ++n) {
                int gc = colBase + wn * 64 + n * 16 + (lane & 15);
                C[(size_t)gr * NN + gc] = acc[m][n][j] + bcol[n];
            }
        }
    }
}

// ------- K2: K feature map (exact) fused with kv/ksum partial sums ---------
__global__ __launch_bounds__(256) void fmap_k_kv(const __hip_bfloat16* __restrict__ Kh,
                                                 const __hip_bfloat16* __restrict__ Vh,
                                                 const float* __restrict__ proj,
                                                 float* __restrict__ kvpart,
                                                 float* __restrict__ kspart) {
    int bh = blockIdx.y, ch = blockIdx.x, h = bh & 15;
    __shared__ __hip_bfloat16 pj[256][70];
    __shared__ float ks_[4][64];
    __shared__ float vs_[4][64];
    __shared__ float kp_[4][256];
    int t = threadIdx.x, lane = t & 63, w = t >> 6;
    for (int i = t; i < 256 * 64; i += 256) {
        int m = i >> 6, dd = i & 63;
        pj[m][dd] = __float2bfloat16(proj[(size_t)h * 16384 + i]);
    }
    float acc[64];
#pragma unroll
    for (int q = 0; q < 64; ++q) acc[q] = 0.f;
    float ksacc = 0.f;
    int rr = t >> 6, dd = t & 63;
    for (int it = 0; it < 128; ++it) {
        int rbase = ch * 512 + it * 4;
        ks_[rr][dd] = __bfloat162float(Kh[((size_t)bh * 4096 + rbase + rr) * 64 + dd]) * DN;
        vs_[rr][dd] = __bfloat162float(Vh[((size_t)bh * 4096 + rbase + rr) * 64 + dd]);
        __syncthreads();
        float xp[4] = {0.f, 0.f, 0.f, 0.f};
        for (int d2 = 0; d2 < 64; d2 += 2) {
            float2 k2 = *(const float2*)&ks_[w][d2];
#pragma unroll
            for (int j = 0; j < 4; ++j) {
                uint32_t u = *(const uint32_t*)&pj[lane + 64 * j][d2];
                xp[j] += k2.x * bflo(u) + k2.y * bfhi(u);
            }
        }
        float kq = ks_[w][lane];
        float sq = kq * kq;
#pragma unroll
        for (int off = 32; off >= 1; off >>= 1) sq += __shfl_xor(sq, off);
        sq *= 0.5f;
        float val[4]; float vm = -1e30f;
#pragma unroll
        for (int j = 0; j < 4; ++j) { val[j] = xp[j] - sq; vm = fmaxf(vm, val[j]); }
#pragma unroll
        for (int off = 32; off >= 1; off >>= 1) vm = fmaxf(vm, __shfl_xor(vm, off));
#pragma unroll
        for (int j = 0; j < 4; ++j)
            kp_[w][lane + 64 * j] = (__expf(val[j] - vm) + EPSF) * INV_SQRT_M;
        __syncthreads();
#pragma unroll
        for (int r = 0; r < 4; ++r) {
            float s = kp_[r][t];
            ksacc += s;
            const float4* v4 = (const float4*)&vs_[r][0];
#pragma unroll
            for (int q = 0; q < 16; ++q) {
                float4 vv = v4[q];
                acc[4 * q + 0] += s * vv.x; acc[4 * q + 1] += s * vv.y;
                acc[4 * q + 2] += s * vv.z; acc[4 * q + 3] += s * vv.w;
            }
        }
        __syncthreads();
    }
    float4* dst4 = (float4*)(kvpart + ((size_t)(bh * 8 + ch)) * 16384 + (size_t)t * 64);
#pragma unroll
    for (int q = 0; q < 16; ++q)
        dst4[q] = make_float4(acc[4 * q], acc[4 * q + 1], acc[4 * q + 2], acc[4 * q + 3]);
    kspart[(bh * 8 + ch) * 256 + t] = ksacc;
}

// ------- K3: reduce partials -> kvT_sw bf16 [bh][80][256] ------------------
// rows 0-63: kvT[d][m] pre-swizzled (m_local ^= (d&7)<<3 within each 128-half)
// row 64: ksum[m] (unswizzled, matches (64&7)==0); rows 65-79: zeros.
__global__ __launch_bounds__(256) void reduce_kv(const float* __restrict__ kvpart,
                                                 const float* __restrict__ kspart,
                                                 short* __restrict__ kvsT) {
    int bh = blockIdx.y, bx = blockIdx.x, t = threadIdx.x;
    if (bx < 4) {
        __shared__ float tile[64][66];
        int mt = bx * 64;
#pragma unroll
        for (int i = 0; i < 16; ++i) {
            int idx = t + i * 256;
            int ml = idx >> 6, d = idx & 63;
            float s = 0.f;
            size_t base = ((size_t)bh * 8) * 16384 + (size_t)(mt + ml) * 64 + d;
#pragma unroll
            for (int c = 0; c < 8; ++c) s += kvpart[base + (size_t)c * 16384];
            tile[d][ml] = s;
        }
        __syncthreads();
#pragma unroll
        for (int i = 0; i < 16; ++i) {
            int idx = t + i * 256;
            int d = idx >> 6, ml = idx & 63;
            int mg = mt + ml;
            int widx = (mg & 128) + ((mg & 127) ^ ((d & 7) << 3));
            kvsT[((size_t)bh * 80 + d) * 256 + widx] = f2bf(tile[d][ml]);
        }
    } else {
        float s = 0.f;
#pragma unroll
        for (int c = 0; c < 8; ++c) s += kspart[((bh * 8 + c) << 8) + t];
        kvsT[((size_t)bh * 80 + 64) * 256 + t] = f2bf(s);
        for (int i = t; i < 15 * 256; i += 256) {
            int r = 65 + (i >> 8), cc = i & 255;
            kvsT[((size_t)bh * 80 + r) * 256 + cc] = 0;
        }
    }
}

// ------- K4: MFMA contract: S^T=mfma(proj,q); P=exp; out=mfma(P,kvT) -------
__global__ __launch_bounds__(256) void contract_mfma(
        const short* __restrict__ Qh,      // pre-swizzled, *DN
        const short* __restrict__ pjb,     // pre-swizzled bf16
        const short* __restrict__ kvsT,    // pre-swizzled bf16 [bh][80][256]
        short* __restrict__ attn) {
    int bh = blockIdx.y, rb = blockIdx.x, h = bh & 15, b = bh >> 4;
    int t = threadIdx.x, lane = t & 63, w = t >> 6;
    __shared__ __align__(16) short qs[64 * 64];    //  8KB [row][d]  (swz)
    __shared__ __align__(16) short pj[128 * 64];   // 16KB [m][d]    (swz)
    __shared__ __align__(16) short Pl[64 * 128];   // 16KB [row][m]  (swz)
    __shared__ __align__(16) short kvl[80 * 128];  // 20KB [d'][m]   (swz)

    // stage qs once: 8 chunks of 1KB; wave w -> chunks {2w, 2w+1}
    {
        const short* src = Qh + ((size_t)bh * 4096 + rb * 64) * 64;
#pragma unroll
        for (int c2 = 0; c2 < 2; ++c2) {
            int c = 2 * w + c2;
            gload16(src + (c * 8 + (lane >> 3)) * 64 + (lane & 7) * 8,
                    qs + c * 512);
        }
    }

    f32x4 acc5[5];
#pragma unroll
    for (int i = 0; i < 5; ++i) acc5[i] = (f32x4){0.f, 0.f, 0.f, 0.f};

    int g = lane >> 4, li = lane & 15;

    for (int half = 0; half < 2; ++half) {
        __syncthreads();                 // previous-half reads done; qs staged
        // stage pj half (16 chunks), kvl half (20 chunks)
        const short* psrc = pjb + (size_t)h * 16384 + half * 8192;
#pragma unroll
        for (int c2 = 0; c2 < 4; ++c2) {
            int c = 4 * w + c2;
            gload16(psrc + (c * 8 + (lane >> 3)) * 64 + (lane & 7) * 8,
                    pj + c * 512);
        }
        const short* ksrc = kvsT + (size_t)bh * 80 * 256 + half * 128;
#pragma unroll
        for (int c2 = 0; c2 < 5; ++c2) {
            int c = 5 * w + c2;
            gload16(ksrc + (c * 4 + (lane >> 4)) * 256 + (lane & 15) * 8,
                    kvl + c * 512);
        }
        __syncthreads();                 // drain DMA (vmcnt0 at barrier)

        // phase A: S^T tile [m: 32w..32w+31][row: 0..63]
        f32x4 sacc[2][4];
#pragma unroll
        for (int mi = 0; mi < 2; ++mi)
#pragma unroll
            for (int ni = 0; ni < 4; ++ni) sacc[mi][ni] = (f32x4){0.f, 0.f, 0.f, 0.f};
#pragma unroll
        for (int ks = 0; ks < 2; ++ks) {
            int kbyte = ks * 64 + g * 16;
            bf16x8 afr[2], bfr[4];
#pragma unroll
            for (int mi = 0; mi < 2; ++mi) {
                int mr = 32 * w + 16 * mi + li;
                afr[mi] = *(const bf16x8*)((const char*)pj +
                           mr * 128 + (kbyte ^ ((mr & 7) << 4)));
            }
#pragma unroll
            for (int ni = 0; ni < 4; ++ni) {
                int qr = 16 * ni + li;
                bfr[ni] = *(const bf16x8*)((const char*)qs +
                           qr * 128 + (kbyte ^ ((qr & 7) << 4)));
            }
#pragma unroll
            for (int mi = 0; mi < 2; ++mi)
#pragma unroll
                for (int ni = 0; ni < 4; ++ni)
                    sacc[mi][ni] = __builtin_amdgcn_mfma_f32_16x16x32_bf16(
                        afr[mi], bfr[ni], sacc[mi][ni], 0, 0, 0);
        }

        // phase B: P = (exp(S)+eps)/sqrt(M) -> bf16, packed b64 writes
#pragma unroll
        for (int mi = 0; mi < 2; ++mi) {
            int m0 = 32 * w + 16 * mi + 4 * g;     // 4 consecutive m (jj)
#pragma unroll
            for (int ni = 0; ni < 4; ++ni) {
                int row = 16 * ni + li;
                float e0 = (__expf(sacc[mi][ni][0]) + EPSF) * INV_SQRT_M;
                float e1 = (__expf(sacc[mi][ni][1]) + EPSF) * INV_SQRT_M;
                float e2 = (__expf(sacc[mi][ni][2]) + EPSF) * INV_SQRT_M;
                float e3 = (__expf(sacc[mi][ni][3]) + EPSF) * INV_SQRT_M;
                uint32_t u0 = (uint32_t)(uint16_t)f2bf(e0) |
                              ((uint32_t)(uint16_t)f2bf(e1) << 16);
                uint32_t u1 = (uint32_t)(uint16_t)f2bf(e2) |
                              ((uint32_t)(uint16_t)f2bf(e3) << 16);
                int byte = row * 256 + ((m0 * 2) ^ ((row & 7) << 4));
                *(uint2*)((char*)Pl + byte) = make_uint2(u0, u1);
            }
        }
        __syncthreads();                 // P visible

        // phase C: out[16w..16w+15][0..79] += P @ kvT (col 64 = den)
        int rowA = 16 * w + li;
        int abase = rowA * 256;
        int asw = (rowA & 7) << 4;
#pragma unroll
        for (int ks = 0; ks < 4; ++ks) {
            int kbyte = ks * 64 + g * 16;
            bf16x8 pa = *(const bf16x8*)((const char*)Pl + abase + (kbyte ^ asw));
#pragma unroll
            for (int ni = 0; ni < 5; ++ni) {
                int rowB = 16 * ni + li;
                bf16x8 bv = *(const bf16x8*)((const char*)kvl +
                             rowB * 256 + (kbyte ^ ((rowB & 7) << 4)));
                acc5[ni] = __builtin_amdgcn_mfma_f32_16x16x32_bf16(
                    pa, bv, acc5[ni], 0, 0, 0);
            }
        }
    }

    // epilogue: den broadcast (lives in lanes li==0 of ni=4 frag), divide, store
    float dj[4];
#pragma unroll
    for (int jj = 0; jj < 4; ++jj)
        dj[jj] = __shfl(acc5[4][jj], lane & 48) + EPSF;
#pragma unroll
    for (int ni = 0; ni < 4; ++ni) {
        int d = 16 * ni + li;
#pragma unroll
        for (int jj = 0; jj < 4; ++jj) {
            int n = rb * 64 + 16 * w + 4 * g + jj;
            attn[((size_t)b * 4096 + n) * 1024 + h * 64 + d] =
                f2bf(acc5[ni][jj] / dj[jj]);
        }
    }
}

extern "C" void kernel_launch(void* const* d_in, const int* in_sizes, int n_in,
                              void* d_out, int out_size, void* d_ws, size_t ws_size,
                              hipStream_t stream) {
    const float* x      = (const float*)d_in[0];
    const float* w_qkv  = (const float*)d_in[1];
    const float* b_qkv  = (const float*)d_in[2];
    const float* w_out  = (const float*)d_in[3];
    const float* b_out  = (const float*)d_in[4];
    const float* proj   = (const float*)d_in[5];
    float* out = (float*)d_out;

    // workspace layout (bytes), total ~139.5 MiB
    char* w = (char*)d_ws;
    short* xb     = (short*)(w);                        // 32 MiB -> kvpart overlay
    short* wqT    = (short*)(w + 33554432);             // 6 MiB
    short* wOT    = (short*)(w + 39845888);             // 2 MiB
    short* Qh     = (short*)(w + 41943040);             // 32 MiB (pre-swz, *DN)
    short* Kh     = (short*)(w + 75497472);             // 32 MiB (-> attn overlay)
    short* Vh     = (short*)(w + 109051904);            // 32 MiB
    float* kvpart = (float*)(w);                        // overlay (xb dead)
    float* kspart = (float*)(w + 142606336);            // 512 KiB
    short* kvsT   = (short*)(w + 143130624);            // 2.5 MiB [64][80][256]
    short* pjb    = (short*)(w + 145752064);            // 512 KiB
    short* attn   = Kh;                                 // overlay (Kh dead)

    conv_x<<<dim3(16384), 256, 0, stream>>>(x, xb);
    convt_w<<<dim3(48, 16), 256, 0, stream>>>(w_qkv, wqT, 1024, 3072);
    convt_w<<<dim3(16, 16), 256, 0, stream>>>(w_out, wOT, 1024, 1024);
    conv_proj<<<dim3(1024), 256, 0, stream>>>(proj, pjb);
    mfma_gemm_qkv<<<dim3(24, 128), 256, 0, stream>>>(xb, wqT, b_qkv, Qh, Kh, Vh);
    fmap_k_kv<<<dim3(8, 64), 256, 0, stream>>>((const __hip_bfloat16*)Kh,
                                               (const __hip_bfloat16*)Vh, proj,
                                               kvpart, kspart);
    reduce_kv<<<dim3(5, 64), 256, 0, stream>>>(kvpart, kspart, kvsT);
    contract_mfma<<<dim3(64, 64), 256, 0, stream>>>(Qh, pjb, kvsT, attn);
    mfma_gemm_out<<<dim3(8, 128), 256, 0, stream>>>(attn, wOT, b_out, out);
}

// Round 5
// 341.646 us; speedup vs baseline: 9.9029x; 2.7970x over previous
//
#include <hip/hip_runtime.h>
#include <hip/hip_bf16.h>
#include <stdint.h>

// ---------------------------------------------------------------------------
// Performer attention, round 4: fmap_k_kv -> MFMA (sq cancels vs rowmax).
// B=4, N=4096, C=1024, H=16, D=64, M=256 features.
//
//  K0a conv_x        : x f32 -> bf16
//  K0b convt_w       : w f32 [K][N] -> bf16 [N][K]
//  K0c conv_proj     : proj f32 -> bf16 [h][m][d^((m&7)<<3)] (pre-swizzled)
//  K1 mfma_gemm_qkv  : xb @ wqT^T + b ->
//                        Q,K bf16 [bh][n][d-swz] prescaled *DN
//                        V  bf16 [bh][d][n-swz] transposed
//  K2 fmap_mfma      : S=mfma(K,proj); rowmax; P=exp(S-max); kv=mfma(P,V^T)
//                      -> kvpart [bh][ch][d][m] f32, kspart
//  K3 reduce_kv      : partials -> kvT_sw bf16 [bh][80][256] (row64=ksum)
//  K4 contract_mfma  : S^T=mfma(proj,q); P=exp; out=mfma(P, kvT) incl den
//  K5 mfma_gemm_out  : attn(bf16) @ wOT^T + b_out -> d_out (f32)
// ---------------------------------------------------------------------------

#define DN 0.35355339059327379f   // 64^-0.25
#define EPSF 1e-6f
#define INV_SQRT_M 0.0625f        // 1/sqrt(256)

typedef __attribute__((ext_vector_type(8))) short bf16x8;
typedef __attribute__((ext_vector_type(4))) float f32x4;

static __device__ __forceinline__ short f2bf(float f) {
    __hip_bfloat16 h = __float2bfloat16(f);
    return *(short*)&h;
}
static __device__ __forceinline__ void gload16(const void* g, void* l) {
    __builtin_amdgcn_global_load_lds(
        (const __attribute__((address_space(1))) void*)g,
        (__attribute__((address_space(3))) void*)l,
        16, 0, 0);
}

// ---------------- K0a: x f32 -> bf16 ---------------------------------------
__global__ __launch_bounds__(256) void conv_x(const float* __restrict__ X,
                                              short* __restrict__ Xb) {
    int i = blockIdx.x * 256 + threadIdx.x;
    float4 v = ((const float4*)X)[i];
    short4 o;
    o.x = f2bf(v.x); o.y = f2bf(v.y); o.z = f2bf(v.z); o.w = f2bf(v.w);
    ((short4*)Xb)[i] = o;
}

// ---------------- K0b: W [K][NN] f32 -> WT [NN][K] bf16 --------------------
__global__ __launch_bounds__(256) void convt_w(const float* __restrict__ W,
                                               short* __restrict__ WT,
                                               int K, int NN) {
    __shared__ short tile[64][66];
    int t = threadIdx.x;
    int k0 = blockIdx.y * 64, n0 = blockIdx.x * 64;
    for (int i = t; i < 4096; i += 256) {
        int r = i >> 6, c = i & 63;
        tile[r][c] = f2bf(W[(size_t)(k0 + r) * NN + n0 + c]);
    }
    __syncthreads();
    for (int i = t; i < 4096; i += 256) {
        int r = i >> 6, c = i & 63;
        WT[(size_t)(n0 + r) * K + k0 + c] = tile[c][r];
    }
}

// ---------------- K0c: proj f32 -> bf16 pre-swizzled -----------------------
__global__ __launch_bounds__(256) void conv_proj(const float* __restrict__ proj,
                                                 short* __restrict__ pjb) {
    int e = blockIdx.x * 256 + threadIdx.x;    // 262144 total
    int m = (e >> 6) & 255, d = e & 63;
    int base = e & ~63;
    pjb[base + (d ^ ((m & 7) << 3))] = f2bf(proj[e]);
}

// ---------------- K1: MFMA GEMM -> Q,K (swz,*DN), V^T ----------------------
__global__ __launch_bounds__(256) void mfma_gemm_qkv(const short* __restrict__ A,
                                                     const short* __restrict__ BT,
                                                     const float* __restrict__ bias,
                                                     short* __restrict__ Qh,
                                                     short* __restrict__ Kh,
                                                     short* __restrict__ Vt) {
    const int K = 1024;
    __shared__ short lA[128 * 32];
    __shared__ short lB[128 * 32];
    int t = threadIdx.x, lane = t & 63, w = t >> 6;
    int wm = w >> 1, wn = w & 1;
    int rowBase = blockIdx.y * 128, colBase = blockIdx.x * 128;

    int rs = (lane >> 2), cb = (lane & 3) * 16;
    const char* gA0 = (const char*)(A + (size_t)(rowBase + w * 32 + rs) * K) + cb;
    const char* gA1 = (const char*)(A + (size_t)(rowBase + w * 32 + 16 + rs) * K) + cb;
    const char* gB0 = (const char*)(BT + (size_t)(colBase + w * 32 + rs) * K) + cb;
    const char* gB1 = (const char*)(BT + (size_t)(colBase + w * 32 + 16 + rs) * K) + cb;
    char* dA0 = (char*)lA + (w * 32) * 64;
    char* dA1 = (char*)lA + (w * 32 + 16) * 64;
    char* dB0 = (char*)lB + (w * 32) * 64;
    char* dB1 = (char*)lB + (w * 32 + 16) * 64;

    int offA[4], offB[4];
#pragma unroll
    for (int m = 0; m < 4; ++m) {
        offA[m] = (wm * 64 + m * 16 + (lane & 15)) * 64 + (lane >> 4) * 16;
        offB[m] = (wn * 64 + m * 16 + (lane & 15)) * 64 + (lane >> 4) * 16;
    }

    f32x4 acc[4][4];
#pragma unroll
    for (int m = 0; m < 4; ++m)
#pragma unroll
        for (int n = 0; n < 4; ++n) acc[m][n] = (f32x4){0.f, 0.f, 0.f, 0.f};

    for (int k0 = 0; k0 < K; k0 += 32) {
        size_t kb = (size_t)k0 * 2;
        gload16(gA0 + kb, dA0);
        gload16(gA1 + kb, dA1);
        gload16(gB0 + kb, dB0);
        gload16(gB1 + kb, dB1);
        __syncthreads();
        bf16x8 af[4], bfr[4];
#pragma unroll
        for (int m = 0; m < 4; ++m) af[m] = *(const bf16x8*)((const char*)lA + offA[m]);
#pragma unroll
        for (int n = 0; n < 4; ++n) bfr[n] = *(const bf16x8*)((const char*)lB + offB[n]);
#pragma unroll
        for (int m = 0; m < 4; ++m)
#pragma unroll
            for (int n = 0; n < 4; ++n)
                acc[m][n] = __builtin_amdgcn_mfma_f32_16x16x32_bf16(af[m], bfr[n], acc[m][n], 0, 0, 0);
        __syncthreads();
    }

    int li = lane & 15, g = lane >> 4;
    float bcol[4];
#pragma unroll
    for (int n = 0; n < 4; ++n)
        bcol[n] = bias[colBase + wn * 64 + n * 16 + li];
#pragma unroll
    for (int n = 0; n < 4; ++n) {
        int gc = colBase + wn * 64 + n * 16 + li;
        int which = gc >> 10, cc = gc & 1023, hh = cc >> 6, dd = cc & 63;
        if (which == 2) {
            // V^T: [bh][dd][4096 n-swz]; pack 4 consecutive n (j) per store
#pragma unroll
            for (int m = 0; m < 4; ++m) {
                int gr0 = rowBase + wm * 64 + m * 16 + g * 4;
                int b = gr0 >> 12, nn0 = gr0 & 4095;
                short4 o;
                o.x = f2bf(acc[m][n][0] + bcol[n]);
                o.y = f2bf(acc[m][n][1] + bcol[n]);
                o.z = f2bf(acc[m][n][2] + bcol[n]);
                o.w = f2bf(acc[m][n][3] + bcol[n]);
                int nsw = (nn0 & ~63) | ((nn0 & 63) ^ ((dd & 7) << 3));
                *(short4*)&Vt[((size_t)(b * 16 + hh) * 64 + dd) * 4096 + nsw] = o;
            }
        } else {
            // Q,K: prescale DN, pre-swizzle d for MFMA LDS reads
            short* dst = (which == 0) ? Qh : Kh;
#pragma unroll
            for (int m = 0; m < 4; ++m) {
#pragma unroll
                for (int j = 0; j < 4; ++j) {
                    int gr = rowBase + wm * 64 + m * 16 + g * 4 + j;
                    int b = gr >> 12, nn = gr & 4095;
                    int dsw = dd ^ ((nn & 7) << 3);
                    dst[((size_t)(b * 16 + hh) * 4096 + nn) * 64 + dsw] =
                        f2bf((acc[m][n][j] + bcol[n]) * DN);
                }
            }
        }
    }
}

// ---------------- K5: MFMA GEMM -> d_out f32 -------------------------------
__global__ __launch_bounds__(256) void mfma_gemm_out(const short* __restrict__ A,
                                                     const short* __restrict__ BT,
                                                     const float* __restrict__ bias,
                                                     float* __restrict__ C) {
    const int K = 1024, NN = 1024;
    __shared__ short lA[128 * 32];
    __shared__ short lB[128 * 32];
    int t = threadIdx.x, lane = t & 63, w = t >> 6;
    int wm = w >> 1, wn = w & 1;
    int rowBase = blockIdx.y * 128, colBase = blockIdx.x * 128;

    int rs = (lane >> 2), cb = (lane & 3) * 16;
    const char* gA0 = (const char*)(A + (size_t)(rowBase + w * 32 + rs) * K) + cb;
    const char* gA1 = (const char*)(A + (size_t)(rowBase + w * 32 + 16 + rs) * K) + cb;
    const char* gB0 = (const char*)(BT + (size_t)(colBase + w * 32 + rs) * K) + cb;
    const char* gB1 = (const char*)(BT + (size_t)(colBase + w * 32 + 16 + rs) * K) + cb;
    char* dA0 = (char*)lA + (w * 32) * 64;
    char* dA1 = (char*)lA + (w * 32 + 16) * 64;
    char* dB0 = (char*)lB + (w * 32) * 64;
    char* dB1 = (char*)lB + (w * 32 + 16) * 64;

    int offA[4], offB[4];
#pragma unroll
    for (int m = 0; m < 4; ++m) {
        offA[m] = (wm * 64 + m * 16 + (lane & 15)) * 64 + (lane >> 4) * 16;
        offB[m] = (wn * 64 + m * 16 + (lane & 15)) * 64 + (lane >> 4) * 16;
    }

    f32x4 acc[4][4];
#pragma unroll
    for (int m = 0; m < 4; ++m)
#pragma unroll
        for (int n = 0; n < 4; ++n) acc[m][n] = (f32x4){0.f, 0.f, 0.f, 0.f};

    for (int k0 = 0; k0 < K; k0 += 32) {
        size_t kb = (size_t)k0 * 2;
        gload16(gA0 + kb, dA0);
        gload16(gA1 + kb, dA1);
        gload16(gB0 + kb, dB0);
        gload16(gB1 + kb, dB1);
        __syncthreads();
        bf16x8 af[4], bfr[4];
#pragma unroll
        for (int m = 0; m < 4; ++m) af[m] = *(const bf16x8*)((const char*)lA + offA[m]);
#pragma unroll
        for (int n = 0; n < 4; ++n) bfr[n] = *(const bf16x8*)((const char*)lB + offB[n]);
#pragma unroll
        for (int m = 0; m < 4; ++m)
#pragma unroll
            for (int n = 0; n < 4; ++n)
                acc[m][n] = __builtin_amdgcn_mfma_f32_16x16x32_bf16(af[m], bfr[n], acc[m][n], 0, 0, 0);
        __syncthreads();
    }

    float bcol[4];
#pragma unroll
    for (int n = 0; n < 4; ++n)
        bcol[n] = bias[colBase + wn * 64 + n * 16 + (lane & 15)];
#pragma unroll
    for (int m = 0; m < 4; ++m) {
#pragma unroll
        for (int j = 0; j < 4; ++j) {
            int gr = rowBase + wm * 64 + m * 16 + (lane >> 4) * 4 + j;
#pragma unroll
            for (int n = 0; n < 4; ++n) {
                int gc = colBase + wn * 64 + n * 16 + (lane & 15);
                C[(size_t)gr * NN + gc] = acc[m][n][j] + bcol[n];
            }
        }
    }
}

// ------- K2: MFMA K feature map + kv/ksum partials -------------------------
// Per 64-row tile: S[n][m]=mfma(K,proj); rowmax over m (exact, reweights
// tokens); P=(exp(S-max)+eps)/16 -> bf16 per-wave LDS; kv+=mfma(P,V^T).
// sq_norms cancels exactly against the rowmax subtraction -> dropped.
__global__ __launch_bounds__(256) void fmap_mfma(const short* __restrict__ Kh,
                                                 const short* __restrict__ Vt,
                                                 const short* __restrict__ pjb,
                                                 float* __restrict__ kvpart,
                                                 float* __restrict__ kspart) {
    int bh = blockIdx.y, ch = blockIdx.x, h = bh & 15;
    int t = threadIdx.x, lane = t & 63, w = t >> 6;
    int g = lane >> 4, li = lane & 15;
    __shared__ __align__(16) short pj[256 * 64];    // 32KB swz
    __shared__ __align__(16) short kt[64 * 64];     //  8KB [n][d] swz
    __shared__ __align__(16) short vt[64 * 64];     //  8KB [d][n] swz
    __shared__ __align__(16) short Pl[4][64 * 40];  // 20KB per-wave, 80B rows
    __shared__ __align__(16) float maxw[4][64];     //  1KB

    // stage proj once (32 chunks of 1KB)
    {
        const short* psrc = pjb + (size_t)h * 16384;
#pragma unroll
        for (int c2 = 0; c2 < 8; ++c2) {
            int c = 8 * w + c2;
            gload16(psrc + c * 512 + lane * 8, pj + c * 512);
        }
    }

    f32x4 acc[4][4];    // kv accumulator [mi][di]
#pragma unroll
    for (int i = 0; i < 4; ++i)
#pragma unroll
        for (int j = 0; j < 4; ++j) acc[i][j] = (f32x4){0.f, 0.f, 0.f, 0.f};
    float ksacc[4] = {0.f, 0.f, 0.f, 0.f};

    const short* kbase = Kh + ((size_t)bh * 4096 + ch * 512) * 64;
    const short* vbase = Vt + (size_t)bh * 64 * 4096 + ch * 512;
    int swz = (li & 7) << 4;

    for (int tile = 0; tile < 8; ++tile) {
        __syncthreads();               // prev-tile reads done (and pj ready)
        // stage K tile (8 chunks) + V^T tile (8 chunks); 2 each per wave
#pragma unroll
        for (int c2 = 0; c2 < 2; ++c2) {
            int c = 2 * w + c2;
            gload16(kbase + (size_t)(tile * 64) * 64 + c * 512 + lane * 8,
                    kt + c * 512);
            int d = 8 * c + (lane >> 3);
            gload16(vbase + (size_t)d * 4096 + tile * 64 + (lane & 7) * 8,
                    vt + c * 512);
        }
        __syncthreads();               // staged (vmcnt drained at barrier)

        // phase A: S[n][m], rows n (A=K), cols m (B=proj, wave slice 64w..)
        f32x4 sacc[4][4];              // [ni][mi]
#pragma unroll
        for (int i = 0; i < 4; ++i)
#pragma unroll
            for (int j = 0; j < 4; ++j) sacc[i][j] = (f32x4){0.f, 0.f, 0.f, 0.f};
#pragma unroll
        for (int ks = 0; ks < 2; ++ks) {
            int kb = ks * 64 + g * 16;
            bf16x8 afr[4], bfr[4];
#pragma unroll
            for (int ni = 0; ni < 4; ++ni)
                afr[ni] = *(const bf16x8*)((const char*)kt +
                           (16 * ni + li) * 128 + (kb ^ swz));
#pragma unroll
            for (int mi = 0; mi < 4; ++mi)
                bfr[mi] = *(const bf16x8*)((const char*)pj +
                           (64 * w + 16 * mi + li) * 128 + (kb ^ swz));
#pragma unroll
            for (int ni = 0; ni < 4; ++ni)
#pragma unroll
                for (int mi = 0; mi < 4; ++mi)
                    sacc[ni][mi] = __builtin_amdgcn_mfma_f32_16x16x32_bf16(
                        afr[ni], bfr[mi], sacc[ni][mi], 0, 0, 0);
        }

        // per-wave max over m for each n = 16ni+4g+jj
        float mxl[4][4];               // [ni][jj]
#pragma unroll
        for (int ni = 0; ni < 4; ++ni)
#pragma unroll
            for (int jj = 0; jj < 4; ++jj) {
                float m0 = fmaxf(sacc[ni][0][jj], sacc[ni][1][jj]);
                float m1 = fmaxf(sacc[ni][2][jj], sacc[ni][3][jj]);
                mxl[ni][jj] = fmaxf(m0, m1);
            }
#pragma unroll
        for (int off = 1; off <= 8; off <<= 1)
#pragma unroll
            for (int ni = 0; ni < 4; ++ni)
#pragma unroll
                for (int jj = 0; jj < 4; ++jj)
                    mxl[ni][jj] = fmaxf(mxl[ni][jj], __shfl_xor(mxl[ni][jj], off));
        if (li == 0) {
#pragma unroll
            for (int ni = 0; ni < 4; ++ni)
                *(float4*)&maxw[w][16 * ni + 4 * g] =
                    make_float4(mxl[ni][0], mxl[ni][1], mxl[ni][2], mxl[ni][3]);
        }
        __syncthreads();               // maxw visible

        // phase B+C interleaved per 32-n half
#pragma unroll
        for (int hf = 0; hf < 2; ++hf) {
#pragma unroll
            for (int ni2 = 0; ni2 < 2; ++ni2) {
                int ni = 2 * hf + ni2;
                float4 a0 = *(const float4*)&maxw[0][16 * ni + 4 * g];
                float4 a1 = *(const float4*)&maxw[1][16 * ni + 4 * g];
                float4 a2 = *(const float4*)&maxw[2][16 * ni + 4 * g];
                float4 a3 = *(const float4*)&maxw[3][16 * ni + 4 * g];
                float mm[4];
                mm[0] = fmaxf(fmaxf(a0.x, a1.x), fmaxf(a2.x, a3.x));
                mm[1] = fmaxf(fmaxf(a0.y, a1.y), fmaxf(a2.y, a3.y));
                mm[2] = fmaxf(fmaxf(a0.z, a1.z), fmaxf(a2.z, a3.z));
                mm[3] = fmaxf(fmaxf(a0.w, a1.w), fmaxf(a2.w, a3.w));
#pragma unroll
                for (int mi = 0; mi < 4; ++mi) {
                    float p0 = (__expf(sacc[ni][mi][0] - mm[0]) + EPSF) * INV_SQRT_M;
                    float p1 = (__expf(sacc[ni][mi][1] - mm[1]) + EPSF) * INV_SQRT_M;
                    float p2 = (__expf(sacc[ni][mi][2] - mm[2]) + EPSF) * INV_SQRT_M;
                    float p3 = (__expf(sacc[ni][mi][3] - mm[3]) + EPSF) * INV_SQRT_M;
                    ksacc[mi] += (p0 + p1) + (p2 + p3);
                    uint32_t u0 = (uint32_t)(uint16_t)f2bf(p0) |
                                  ((uint32_t)(uint16_t)f2bf(p1) << 16);
                    uint32_t u1 = (uint32_t)(uint16_t)f2bf(p2) |
                                  ((uint32_t)(uint16_t)f2bf(p3) << 16);
                    int m_l = 16 * mi + li;
                    *(uint2*)((char*)Pl[w] + m_l * 80 + 32 * ni2 + 8 * g) =
                        make_uint2(u0, u1);
                }
            }
            // phase C: kv[m][d] += P @ V^T over n-half hf (within-wave LDS dep)
#pragma unroll
            for (int mi = 0; mi < 4; ++mi) {
                bf16x8 pa = *(const bf16x8*)((const char*)Pl[w] +
                             (16 * mi + li) * 80 + 16 * g);
#pragma unroll
                for (int di = 0; di < 4; ++di) {
                    bf16x8 bv = *(const bf16x8*)((const char*)vt +
                                 (16 * di + li) * 128 + ((64 * hf + 16 * g) ^ swz));
                    acc[mi][di] = __builtin_amdgcn_mfma_f32_16x16x32_bf16(
                        pa, bv, acc[mi][di], 0, 0, 0);
                }
            }
        }
    }

    // epilogue: ksum partial (reduce over g), kv partial [d][m]-major
#pragma unroll
    for (int mi = 0; mi < 4; ++mi) {
        ksacc[mi] += __shfl_xor(ksacc[mi], 16);
        ksacc[mi] += __shfl_xor(ksacc[mi], 32);
    }
    if (lane < 16) {
#pragma unroll
        for (int mi = 0; mi < 4; ++mi)
            kspart[(bh * 8 + ch) * 256 + 64 * w + 16 * mi + li] = ksacc[mi];
    }
    float* kvb = kvpart + (size_t)(bh * 8 + ch) * 16384;
#pragma unroll
    for (int mi = 0; mi < 4; ++mi)
#pragma unroll
        for (int di = 0; di < 4; ++di) {
            int d = 16 * di + li, m0 = 64 * w + 16 * mi + 4 * g;
            *(float4*)&kvb[d * 256 + m0] =
                make_float4(acc[mi][di][0], acc[mi][di][1],
                            acc[mi][di][2], acc[mi][di][3]);
        }
}

// ------- K3: reduce partials -> kvT_sw bf16 [bh][80][256] ------------------
// kvpart is [bh][ch][d][m] (already transposed). row 64 = ksum; 65-79 zero.
__global__ __launch_bounds__(256) void reduce_kv(const float* __restrict__ kvpart,
                                                 const float* __restrict__ kspart,
                                                 short* __restrict__ kvsT) {
    int bh = blockIdx.y, bx = blockIdx.x, t = threadIdx.x;
    if (bx < 4) {
#pragma unroll
        for (int i = 0; i < 16; ++i) {
            int idx = t + i * 256;               // 0..4095
            int d = 16 * bx + (idx >> 8), m = idx & 255;
            float s = 0.f;
            size_t base = ((size_t)(bh * 8) * 64 + d) * 256 + m;
#pragma unroll
            for (int c = 0; c < 8; ++c) s += kvpart[base + (size_t)c * 16384];
            int widx = (m & 128) + ((m & 127) ^ ((d & 7) << 3));
            kvsT[((size_t)bh * 80 + d) * 256 + widx] = f2bf(s);
        }
    } else {
        float s = 0.f;
#pragma unroll
        for (int c = 0; c < 8; ++c) s += kspart[((bh * 8 + c) << 8) + t];
        kvsT[((size_t)bh * 80 + 64) * 256 + t] = f2bf(s);
        for (int i = t; i < 15 * 256; i += 256) {
            int r = 65 + (i >> 8), cc = i & 255;
            kvsT[((size_t)bh * 80 + r) * 256 + cc] = 0;
        }
    }
}

// ------- K4: MFMA contract: S^T=mfma(proj,q); P=exp; out=mfma(P,kvT) -------
__global__ __launch_bounds__(256) void contract_mfma(
        const short* __restrict__ Qh,      // pre-swizzled, *DN
        const short* __restrict__ pjb,     // pre-swizzled bf16
        const short* __restrict__ kvsT,    // pre-swizzled bf16 [bh][80][256]
        short* __restrict__ attn) {
    int bh = blockIdx.y, rb = blockIdx.x, h = bh & 15, b = bh >> 4;
    int t = threadIdx.x, lane = t & 63, w = t >> 6;
    __shared__ __align__(16) short qs[64 * 64];    //  8KB [row][d]  (swz)
    __shared__ __align__(16) short pj[128 * 64];   // 16KB [m][d]    (swz)
    __shared__ __align__(16) short Pl[64 * 128];   // 16KB [row][m]  (swz)
    __shared__ __align__(16) short kvl[80 * 128];  // 20KB [d'][m]   (swz)

    {
        const short* src = Qh + ((size_t)bh * 4096 + rb * 64) * 64;
#pragma unroll
        for (int c2 = 0; c2 < 2; ++c2) {
            int c = 2 * w + c2;
            gload16(src + (c * 8 + (lane >> 3)) * 64 + (lane & 7) * 8,
                    qs + c * 512);
        }
    }

    f32x4 acc5[5];
#pragma unroll
    for (int i = 0; i < 5; ++i) acc5[i] = (f32x4){0.f, 0.f, 0.f, 0.f};

    int g = lane >> 4, li = lane & 15;

    for (int half = 0; half < 2; ++half) {
        __syncthreads();
        const short* psrc = pjb + (size_t)h * 16384 + half * 8192;
#pragma unroll
        for (int c2 = 0; c2 < 4; ++c2) {
            int c = 4 * w + c2;
            gload16(psrc + (c * 8 + (lane >> 3)) * 64 + (lane & 7) * 8,
                    pj + c * 512);
        }
        const short* ksrc = kvsT + (size_t)bh * 80 * 256 + half * 128;
#pragma unroll
        for (int c2 = 0; c2 < 5; ++c2) {
            int c = 5 * w + c2;
            gload16(ksrc + (c * 4 + (lane >> 4)) * 256 + (lane & 15) * 8,
                    kvl + c * 512);
        }
        __syncthreads();

        f32x4 sacc[2][4];
#pragma unroll
        for (int mi = 0; mi < 2; ++mi)
#pragma unroll
            for (int ni = 0; ni < 4; ++ni) sacc[mi][ni] = (f32x4){0.f, 0.f, 0.f, 0.f};
#pragma unroll
        for (int ks = 0; ks < 2; ++ks) {
            int kbyte = ks * 64 + g * 16;
            bf16x8 afr[2], bfr[4];
#pragma unroll
            for (int mi = 0; mi < 2; ++mi) {
                int mr = 32 * w + 16 * mi + li;
                afr[mi] = *(const bf16x8*)((const char*)pj +
                           mr * 128 + (kbyte ^ ((mr & 7) << 4)));
            }
#pragma unroll
            for (int ni = 0; ni < 4; ++ni) {
                int qr = 16 * ni + li;
                bfr[ni] = *(const bf16x8*)((const char*)qs +
                           qr * 128 + (kbyte ^ ((qr & 7) << 4)));
            }
#pragma unroll
            for (int mi = 0; mi < 2; ++mi)
#pragma unroll
                for (int ni = 0; ni < 4; ++ni)
                    sacc[mi][ni] = __builtin_amdgcn_mfma_f32_16x16x32_bf16(
                        afr[mi], bfr[ni], sacc[mi][ni], 0, 0, 0);
        }

#pragma unroll
        for (int mi = 0; mi < 2; ++mi) {
            int m0 = 32 * w + 16 * mi + 4 * g;
#pragma unroll
            for (int ni = 0; ni < 4; ++ni) {
                int row = 16 * ni + li;
                float e0 = (__expf(sacc[mi][ni][0]) + EPSF) * INV_SQRT_M;
                float e1 = (__expf(sacc[mi][ni][1]) + EPSF) * INV_SQRT_M;
                float e2 = (__expf(sacc[mi][ni][2]) + EPSF) * INV_SQRT_M;
                float e3 = (__expf(sacc[mi][ni][3]) + EPSF) * INV_SQRT_M;
                uint32_t u0 = (uint32_t)(uint16_t)f2bf(e0) |
                              ((uint32_t)(uint16_t)f2bf(e1) << 16);
                uint32_t u1 = (uint32_t)(uint16_t)f2bf(e2) |
                              ((uint32_t)(uint16_t)f2bf(e3) << 16);
                int byte = row * 256 + ((m0 * 2) ^ ((row & 7) << 4));
                *(uint2*)((char*)Pl + byte) = make_uint2(u0, u1);
            }
        }
        __syncthreads();

        int rowA = 16 * w + li;
        int abase = rowA * 256;
        int asw = (rowA & 7) << 4;
#pragma unroll
        for (int ks = 0; ks < 4; ++ks) {
            int kbyte = ks * 64 + g * 16;
            bf16x8 pa = *(const bf16x8*)((const char*)Pl + abase + (kbyte ^ asw));
#pragma unroll
            for (int ni = 0; ni < 5; ++ni) {
                int rowB = 16 * ni + li;
                bf16x8 bv = *(const bf16x8*)((const char*)kvl +
                             rowB * 256 + (kbyte ^ ((rowB & 7) << 4)));
                acc5[ni] = __builtin_amdgcn_mfma_f32_16x16x32_bf16(
                    pa, bv, acc5[ni], 0, 0, 0);
            }
        }
    }

    float dj[4];
#pragma unroll
    for (int jj = 0; jj < 4; ++jj)
        dj[jj] = __shfl(acc5[4][jj], lane & 48) + EPSF;
#pragma unroll
    for (int ni = 0; ni < 4; ++ni) {
        int d = 16 * ni + li;
#pragma unroll
        for (int jj = 0; jj < 4; ++jj) {
            int n = rb * 64 + 16 * w + 4 * g + jj;
            attn[((size_t)b * 4096 + n) * 1024 + h * 64 + d] =
                f2bf(acc5[ni][jj] / dj[jj]);
        }
    }
}

extern "C" void kernel_launch(void* const* d_in, const int* in_sizes, int n_in,
                              void* d_out, int out_size, void* d_ws, size_t ws_size,
                              hipStream_t stream) {
    const float* x      = (const float*)d_in[0];
    const float* w_qkv  = (const float*)d_in[1];
    const float* b_qkv  = (const float*)d_in[2];
    const float* w_out  = (const float*)d_in[3];
    const float* b_out  = (const float*)d_in[4];
    const float* proj   = (const float*)d_in[5];
    float* out = (float*)d_out;

    // workspace layout (bytes), total ~139.5 MiB
    char* w = (char*)d_ws;
    short* xb     = (short*)(w);                        // 32 MiB -> kvpart overlay
    short* wqT    = (short*)(w + 33554432);             // 6 MiB
    short* wOT    = (short*)(w + 39845888);             // 2 MiB
    short* Qh     = (short*)(w + 41943040);             // 32 MiB (swz, *DN)
    short* Kh     = (short*)(w + 75497472);             // 32 MiB (swz, *DN) -> attn
    short* Vt     = (short*)(w + 109051904);            // 32 MiB transposed n-swz
    float* kvpart = (float*)(w);                        // overlay (xb dead)
    float* kspart = (float*)(w + 142606336);            // 512 KiB
    short* kvsT   = (short*)(w + 143130624);            // 2.5 MiB [64][80][256]
    short* pjb    = (short*)(w + 145752064);            // 512 KiB
    short* attn   = Kh;                                 // overlay (Kh dead)

    conv_x<<<dim3(16384), 256, 0, stream>>>(x, xb);
    convt_w<<<dim3(48, 16), 256, 0, stream>>>(w_qkv, wqT, 1024, 3072);
    convt_w<<<dim3(16, 16), 256, 0, stream>>>(w_out, wOT, 1024, 1024);
    conv_proj<<<dim3(1024), 256, 0, stream>>>(proj, pjb);
    mfma_gemm_qkv<<<dim3(24, 128), 256, 0, stream>>>(xb, wqT, b_qkv, Qh, Kh, Vt);
    fmap_mfma<<<dim3(8, 64), 256, 0, stream>>>(Kh, Vt, pjb, kvpart, kspart);
    reduce_kv<<<dim3(5, 64), 256, 0, stream>>>(kvpart, kspart, kvsT);
    contract_mfma<<<dim3(64, 64), 256, 0, stream>>>(Qh, pjb, kvsT, attn);
    mfma_gemm_out<<<dim3(8, 128), 256, 0, stream>>>(attn, wOT, b_out, out);
}

// Round 6
// 333.295 us; speedup vs baseline: 10.1510x; 1.0251x over previous
//
#include <hip/hip_runtime.h>
#include <hip/hip_bf16.h>
#include <stdint.h>

// ---------------------------------------------------------------------------
// Performer attention, round 5: counted-vmcnt dbuf GEMMs + T2 swizzle + repack.
// B=4, N=4096, C=1024, H=16, D=64, M=256 features.
//
//  K0a conv_x        : x f32 -> bf16
//  K0b convt_w       : w f32 [K][N] -> bf16 [N][K]
//  K0c conv_proj     : proj f32 -> bf16 [h][m][d^((m&7)<<3)] (pre-swizzled)
//  K1 mfma_gemm_qkv  : pipelined 128x128/BK64 dbuf, vmcnt(8) counted, T2 swz
//                        Q,K bf16 [bh][n][d-swz] *DN ; V bf16 [bh][d][n-swz]
//  K2 fmap_mfma      : S=mfma(K,proj); rowmax; P=exp(S-max); kv=mfma(P,V^T)
//  K3 reduce_kv      : partials -> kvT_sw bf16 [bh][80][256] (row64=ksum)
//  K4 contract_mfma  : S^T=mfma(proj,q); P=exp; out=mfma(P, kvT) incl den
//  K5 mfma_gemm_out  : same pipelined structure -> d_out f32
// ---------------------------------------------------------------------------

#define DN 0.35355339059327379f   // 64^-0.25
#define EPSF 1e-6f
#define INV_SQRT_M 0.0625f        // 1/sqrt(256)

typedef __attribute__((ext_vector_type(8))) short bf16x8;
typedef __attribute__((ext_vector_type(4))) float f32x4;

static __device__ __forceinline__ short f2bf(float f) {
    __hip_bfloat16 h = __float2bfloat16(f);
    return *(short*)&h;
}
static __device__ __forceinline__ void gload16(const void* g, void* l) {
    __builtin_amdgcn_global_load_lds(
        (const __attribute__((address_space(1))) void*)g,
        (__attribute__((address_space(3))) void*)l,
        16, 0, 0);
}

// ---------------- K0a: x f32 -> bf16 ---------------------------------------
__global__ __launch_bounds__(256) void conv_x(const float* __restrict__ X,
                                              short* __restrict__ Xb) {
    int i = blockIdx.x * 256 + threadIdx.x;
    float4 v = ((const float4*)X)[i];
    short4 o;
    o.x = f2bf(v.x); o.y = f2bf(v.y); o.z = f2bf(v.z); o.w = f2bf(v.w);
    ((short4*)Xb)[i] = o;
}

// ---------------- K0b: W [K][NN] f32 -> WT [NN][K] bf16 --------------------
__global__ __launch_bounds__(256) void convt_w(const float* __restrict__ W,
                                               short* __restrict__ WT,
                                               int K, int NN) {
    __shared__ short tile[64][66];
    int t = threadIdx.x;
    int k0 = blockIdx.y * 64, n0 = blockIdx.x * 64;
    for (int i = t; i < 4096; i += 256) {
        int r = i >> 6, c = i & 63;
        tile[r][c] = f2bf(W[(size_t)(k0 + r) * NN + n0 + c]);
    }
    __syncthreads();
    for (int i = t; i < 4096; i += 256) {
        int r = i >> 6, c = i & 63;
        WT[(size_t)(n0 + r) * K + k0 + c] = tile[c][r];
    }
}

// ---------------- K0c: proj f32 -> bf16 pre-swizzled -----------------------
__global__ __launch_bounds__(256) void conv_proj(const float* __restrict__ proj,
                                                 short* __restrict__ pjb) {
    int e = blockIdx.x * 256 + threadIdx.x;    // 262144 total
    int m = (e >> 6) & 255, d = e & 63;
    int base = e & ~63;
    pjb[base + (d ^ ((m & 7) << 3))] = f2bf(proj[e]);
}

// ------- shared pipelined 128x128 GEMM core (BK=64, dbuf, vmcnt(8)) --------
// smem layout: [buf 0/1][A 16KB | B 16KB], 64KB total.
// T2: LDS dest linear; source k-granule XOR'd by (row&7); frag reads XOR back.
__device__ __forceinline__ void gemm_core128(const short* __restrict__ A,
                                             const short* __restrict__ BT,
                                             int rowBase, int colBase,
                                             char* smem, f32x4 acc[4][4]) {
    const int K = 1024;
    int t = threadIdx.x, lane = t & 63, w = t >> 6;
    int li = lane & 15, g = lane >> 4;
    int wm = w >> 1, wn = w & 1;

    const char* aSrc[4]; const char* bSrc[4]; int aOff[4];
#pragma unroll
    for (int c = 0; c < 4; ++c) {
        int idx = c * 256 + t;
        int r = idx >> 3, s = t & 7;          // s == idx&7 (256 % 8 == 0)
        aOff[c] = idx * 16;
        aSrc[c] = (const char*)(A + (size_t)(rowBase + r) * K + ((s ^ (r & 7)) * 8));
        bSrc[c] = (const char*)(BT + (size_t)(colBase + r) * K + ((s ^ (r & 7)) * 8));
    }
#pragma unroll
    for (int m = 0; m < 4; ++m)
#pragma unroll
        for (int n = 0; n < 4; ++n) acc[m][n] = (f32x4){0.f, 0.f, 0.f, 0.f};

    // prologue: stage tile 0 into buf 0
#pragma unroll
    for (int c = 0; c < 4; ++c) {
        gload16(aSrc[c], smem + aOff[c]);
        gload16(bSrc[c], smem + 16384 + aOff[c]);
    }

    int swz = (li & 7) << 4;   // (row&7)<<4 with row = *16 + li -> row&7 == li&7

    for (int tt = 0; tt < 16; ++tt) {
        int cur = tt & 1;
        if (tt < 15) {
            char* d = smem + (cur ^ 1) * 32768;
#pragma unroll
            for (int c = 0; c < 4; ++c) {
                gload16(aSrc[c] + (size_t)(tt + 1) * 128, d + aOff[c]);
                gload16(bSrc[c] + (size_t)(tt + 1) * 128, d + 16384 + aOff[c]);
            }
            asm volatile("s_waitcnt vmcnt(8)" ::: "memory");  // cur tile landed
        } else {
            asm volatile("s_waitcnt vmcnt(0)" ::: "memory");
        }
        __builtin_amdgcn_sched_barrier(0);
        __builtin_amdgcn_s_barrier();
        __builtin_amdgcn_sched_barrier(0);
        __builtin_amdgcn_s_setprio(1);
        const char* bA = smem + cur * 32768;
        const char* bB = bA + 16384;
#pragma unroll
        for (int ks = 0; ks < 2; ++ks) {
            int kb = ks * 64 + g * 16;
            bf16x8 af[4], bv[4];
#pragma unroll
            for (int m = 0; m < 4; ++m)
                af[m] = *(const bf16x8*)(bA + (wm * 64 + m * 16 + li) * 128 + (kb ^ swz));
#pragma unroll
            for (int n = 0; n < 4; ++n)
                bv[n] = *(const bf16x8*)(bB + (wn * 64 + n * 16 + li) * 128 + (kb ^ swz));
#pragma unroll
            for (int m = 0; m < 4; ++m)
#pragma unroll
                for (int n = 0; n < 4; ++n)
                    acc[m][n] = __builtin_amdgcn_mfma_f32_16x16x32_bf16(
                        af[m], bv[n], acc[m][n], 0, 0, 0);
        }
        __builtin_amdgcn_s_setprio(0);
        __builtin_amdgcn_sched_barrier(0);
        __builtin_amdgcn_s_barrier();       // reads done before next overwrite
        __builtin_amdgcn_sched_barrier(0);
    }
}

// ---------------- K1: pipelined MFMA GEMM -> Q,K (swz,*DN), V^T ------------
__global__ __launch_bounds__(256, 2) void mfma_gemm_qkv(
        const short* __restrict__ A, const short* __restrict__ BT,
        const float* __restrict__ bias,
        short* __restrict__ Qh, short* __restrict__ Kh, short* __restrict__ Vt) {
    __shared__ __align__(16) char smem[65536];
    int t = threadIdx.x, lane = t & 63, w = t >> 6;
    int li = lane & 15, g = lane >> 4, wm = w >> 1, wn = w & 1;
    int lin = blockIdx.x;                        // 3072 = 24 x 128
    int sz = (lin & 7) * 384 + (lin >> 3);       // XCD-chunked swizzle
    int bx = sz % 24, by = sz / 24;
    int rowBase = by * 128, colBase = bx * 128;

    f32x4 acc[4][4];
    gemm_core128(A, BT, rowBase, colBase, smem, acc);

    float bcol[4];
#pragma unroll
    for (int n = 0; n < 4; ++n) bcol[n] = bias[colBase + wn * 64 + n * 16 + li];
    int whichB = colBase >> 10;                  // uniform per block (24 = 8+8+8)

    if (whichB == 2) {
        // V^T: [bh][dd][4096 n-swz]; 4 consecutive tokens per short4
#pragma unroll
        for (int n = 0; n < 4; ++n) {
            int gc = colBase + wn * 64 + n * 16 + li;
            int hh = (gc & 1023) >> 6, dd = gc & 63;
#pragma unroll
            for (int m = 0; m < 4; ++m) {
                int gr0 = rowBase + wm * 64 + m * 16 + g * 4;
                int b = gr0 >> 12, nn0 = gr0 & 4095;
                short4 o;
                o.x = f2bf(acc[m][n][0] + bcol[n]);
                o.y = f2bf(acc[m][n][1] + bcol[n]);
                o.z = f2bf(acc[m][n][2] + bcol[n]);
                o.w = f2bf(acc[m][n][3] + bcol[n]);
                int nsw = (nn0 & ~63) | ((nn0 & 63) ^ ((dd & 7) << 3));
                *(short4*)&Vt[((size_t)(b * 16 + hh) * 64 + dd) * 4096 + nsw] = o;
            }
        }
    } else {
        // Q/K: LDS repack (per-wave region) -> 16B swizzled-group stores
        short* dst = (whichB == 0) ? Qh : Kh;
        int hh = ((colBase + wn * 64) & 1023) >> 6;
        float* wreg = (float*)(smem + w * 8704);   // [32][68] f32
#pragma unroll
        for (int r = 0; r < 2; ++r) {
#pragma unroll
            for (int mi = 0; mi < 2; ++mi)
#pragma unroll
                for (int n = 0; n < 4; ++n)
#pragma unroll
                    for (int jj = 0; jj < 4; ++jj)
                        wreg[(mi * 16 + g * 4 + jj) * 68 + n * 16 + li] =
                            (acc[2 * r + mi][n][jj] + bcol[n]) * DN;
            int row = lane >> 1, h2 = lane & 1;
            int tok = rowBase + wm * 64 + r * 32 + row;
            int b = tok >> 12, nn = tok & 4095;
            size_t base = ((size_t)(b * 16 + hh) * 4096 + nn) * 64;
#pragma unroll
            for (int k = 0; k < 4; ++k) {
                float4 v0 = *(const float4*)&wreg[row * 68 + h2 * 32 + k * 8];
                float4 v1 = *(const float4*)&wreg[row * 68 + h2 * 32 + k * 8 + 4];
                bf16x8 ov;
                ov[0] = f2bf(v0.x); ov[1] = f2bf(v0.y);
                ov[2] = f2bf(v0.z); ov[3] = f2bf(v0.w);
                ov[4] = f2bf(v1.x); ov[5] = f2bf(v1.y);
                ov[6] = f2bf(v1.z); ov[7] = f2bf(v1.w);
                int dgrp = (h2 * 4 + k) ^ (tok & 7);
                *(bf16x8*)&dst[base + dgrp * 8] = ov;
            }
        }
    }
}

// ---------------- K5: pipelined MFMA GEMM -> d_out f32 ---------------------
__global__ __launch_bounds__(256, 2) void mfma_gemm_out(
        const short* __restrict__ A, const short* __restrict__ BT,
        const float* __restrict__ bias, float* __restrict__ C) {
    __shared__ __align__(16) char smem[65536];
    int t = threadIdx.x, lane = t & 63, w = t >> 6;
    int li = lane & 15, g = lane >> 4, wm = w >> 1, wn = w & 1;
    int lin = blockIdx.x;                        // 1024 = 8 x 128
    int sz = (lin & 7) * 128 + (lin >> 3);
    int bx = sz & 7, by = sz >> 3;
    int rowBase = by * 128, colBase = bx * 128;

    f32x4 acc[4][4];
    gemm_core128(A, BT, rowBase, colBase, smem, acc);

    float bcol[4];
#pragma unroll
    for (int n = 0; n < 4; ++n) bcol[n] = bias[colBase + wn * 64 + n * 16 + li];
    float* wreg = (float*)(smem + w * 8704);     // [32][68] f32
#pragma unroll
    for (int r = 0; r < 2; ++r) {
#pragma unroll
        for (int mi = 0; mi < 2; ++mi)
#pragma unroll
            for (int n = 0; n < 4; ++n)
#pragma unroll
                for (int jj = 0; jj < 4; ++jj)
                    wreg[(mi * 16 + g * 4 + jj) * 68 + n * 16 + li] =
                        acc[2 * r + mi][n][jj] + bcol[n];
        int row = lane >> 1, h2 = lane & 1;
        int gr = rowBase + wm * 64 + r * 32 + row;
        float* cp = C + (size_t)gr * 1024 + colBase + wn * 64 + h2 * 32;
#pragma unroll
        for (int k = 0; k < 8; ++k)
            *(float4*)&cp[k * 4] = *(const float4*)&wreg[row * 68 + h2 * 32 + k * 4];
    }
}

// ------- K2: MFMA K feature map + kv/ksum partials (unchanged) -------------
__global__ __launch_bounds__(256) void fmap_mfma(const short* __restrict__ Kh,
                                                 const short* __restrict__ Vt,
                                                 const short* __restrict__ pjb,
                                                 float* __restrict__ kvpart,
                                                 float* __restrict__ kspart) {
    int bh = blockIdx.y, ch = blockIdx.x, h = bh & 15;
    int t = threadIdx.x, lane = t & 63, w = t >> 6;
    int g = lane >> 4, li = lane & 15;
    __shared__ __align__(16) short pj[256 * 64];    // 32KB swz
    __shared__ __align__(16) short kt[64 * 64];     //  8KB [n][d] swz
    __shared__ __align__(16) short vt[64 * 64];     //  8KB [d][n] swz
    __shared__ __align__(16) short Pl[4][64 * 40];  // 20KB per-wave, 80B rows
    __shared__ __align__(16) float maxw[4][64];     //  1KB

    {
        const short* psrc = pjb + (size_t)h * 16384;
#pragma unroll
        for (int c2 = 0; c2 < 8; ++c2) {
            int c = 8 * w + c2;
            gload16(psrc + c * 512 + lane * 8, pj + c * 512);
        }
    }

    f32x4 acc[4][4];    // kv accumulator [mi][di]
#pragma unroll
    for (int i = 0; i < 4; ++i)
#pragma unroll
        for (int j = 0; j < 4; ++j) acc[i][j] = (f32x4){0.f, 0.f, 0.f, 0.f};
    float ksacc[4] = {0.f, 0.f, 0.f, 0.f};

    const short* kbase = Kh + ((size_t)bh * 4096 + ch * 512) * 64;
    const short* vbase = Vt + (size_t)bh * 64 * 4096 + ch * 512;
    int swz = (li & 7) << 4;

    for (int tile = 0; tile < 8; ++tile) {
        __syncthreads();
#pragma unroll
        for (int c2 = 0; c2 < 2; ++c2) {
            int c = 2 * w + c2;
            gload16(kbase + (size_t)(tile * 64) * 64 + c * 512 + lane * 8,
                    kt + c * 512);
            int d = 8 * c + (lane >> 3);
            gload16(vbase + (size_t)d * 4096 + tile * 64 + (lane & 7) * 8,
                    vt + c * 512);
        }
        __syncthreads();

        f32x4 sacc[4][4];              // [ni][mi]
#pragma unroll
        for (int i = 0; i < 4; ++i)
#pragma unroll
            for (int j = 0; j < 4; ++j) sacc[i][j] = (f32x4){0.f, 0.f, 0.f, 0.f};
#pragma unroll
        for (int ks = 0; ks < 2; ++ks) {
            int kb = ks * 64 + g * 16;
            bf16x8 afr[4], bfr[4];
#pragma unroll
            for (int ni = 0; ni < 4; ++ni)
                afr[ni] = *(const bf16x8*)((const char*)kt +
                           (16 * ni + li) * 128 + (kb ^ swz));
#pragma unroll
            for (int mi = 0; mi < 4; ++mi)
                bfr[mi] = *(const bf16x8*)((const char*)pj +
                           (64 * w + 16 * mi + li) * 128 + (kb ^ swz));
#pragma unroll
            for (int ni = 0; ni < 4; ++ni)
#pragma unroll
                for (int mi = 0; mi < 4; ++mi)
                    sacc[ni][mi] = __builtin_amdgcn_mfma_f32_16x16x32_bf16(
                        afr[ni], bfr[mi], sacc[ni][mi], 0, 0, 0);
        }

        float mxl[4][4];               // [ni][jj]
#pragma unroll
        for (int ni = 0; ni < 4; ++ni)
#pragma unroll
            for (int jj = 0; jj < 4; ++jj) {
                float m0 = fmaxf(sacc[ni][0][jj], sacc[ni][1][jj]);
                float m1 = fmaxf(sacc[ni][2][jj], sacc[ni][3][jj]);
                mxl[ni][jj] = fmaxf(m0, m1);
            }
#pragma unroll
        for (int off = 1; off <= 8; off <<= 1)
#pragma unroll
            for (int ni = 0; ni < 4; ++ni)
#pragma unroll
                for (int jj = 0; jj < 4; ++jj)
                    mxl[ni][jj] = fmaxf(mxl[ni][jj], __shfl_xor(mxl[ni][jj], off));
        if (li == 0) {
#pragma unroll
            for (int ni = 0; ni < 4; ++ni)
                *(float4*)&maxw[w][16 * ni + 4 * g] =
                    make_float4(mxl[ni][0], mxl[ni][1], mxl[ni][2], mxl[ni][3]);
        }
        __syncthreads();

#pragma unroll
        for (int hf = 0; hf < 2; ++hf) {
#pragma unroll
            for (int ni2 = 0; ni2 < 2; ++ni2) {
                int ni = 2 * hf + ni2;
                float4 a0 = *(const float4*)&maxw[0][16 * ni + 4 * g];
                float4 a1 = *(const float4*)&maxw[1][16 * ni + 4 * g];
                float4 a2 = *(const float4*)&maxw[2][16 * ni + 4 * g];
                float4 a3 = *(const float4*)&maxw[3][16 * ni + 4 * g];
                float mm[4];
                mm[0] = fmaxf(fmaxf(a0.x, a1.x), fmaxf(a2.x, a3.x));
                mm[1] = fmaxf(fmaxf(a0.y, a1.y), fmaxf(a2.y, a3.y));
                mm[2] = fmaxf(fmaxf(a0.z, a1.z), fmaxf(a2.z, a3.z));
                mm[3] = fmaxf(fmaxf(a0.w, a1.w), fmaxf(a2.w, a3.w));
#pragma unroll
                for (int mi = 0; mi < 4; ++mi) {
                    float p0 = (__expf(sacc[ni][mi][0] - mm[0]) + EPSF) * INV_SQRT_M;
                    float p1 = (__expf(sacc[ni][mi][1] - mm[1]) + EPSF) * INV_SQRT_M;
                    float p2 = (__expf(sacc[ni][mi][2] - mm[2]) + EPSF) * INV_SQRT_M;
                    float p3 = (__expf(sacc[ni][mi][3] - mm[3]) + EPSF) * INV_SQRT_M;
                    ksacc[mi] += (p0 + p1) + (p2 + p3);
                    uint32_t u0 = (uint32_t)(uint16_t)f2bf(p0) |
                                  ((uint32_t)(uint16_t)f2bf(p1) << 16);
                    uint32_t u1 = (uint32_t)(uint16_t)f2bf(p2) |
                                  ((uint32_t)(uint16_t)f2bf(p3) << 16);
                    int m_l = 16 * mi + li;
                    *(uint2*)((char*)Pl[w] + m_l * 80 + 32 * ni2 + 8 * g) =
                        make_uint2(u0, u1);
                }
            }
#pragma unroll
            for (int mi = 0; mi < 4; ++mi) {
                bf16x8 pa = *(const bf16x8*)((const char*)Pl[w] +
                             (16 * mi + li) * 80 + 16 * g);
#pragma unroll
                for (int di = 0; di < 4; ++di) {
                    bf16x8 bv = *(const bf16x8*)((const char*)vt +
                                 (16 * di + li) * 128 + ((64 * hf + 16 * g) ^ swz));
                    acc[mi][di] = __builtin_amdgcn_mfma_f32_16x16x32_bf16(
                        pa, bv, acc[mi][di], 0, 0, 0);
                }
            }
        }
    }

#pragma unroll
    for (int mi = 0; mi < 4; ++mi) {
        ksacc[mi] += __shfl_xor(ksacc[mi], 16);
        ksacc[mi] += __shfl_xor(ksacc[mi], 32);
    }
    if (lane < 16) {
#pragma unroll
        for (int mi = 0; mi < 4; ++mi)
            kspart[(bh * 8 + ch) * 256 + 64 * w + 16 * mi + li] = ksacc[mi];
    }
    float* kvb = kvpart + (size_t)(bh * 8 + ch) * 16384;
#pragma unroll
    for (int mi = 0; mi < 4; ++mi)
#pragma unroll
        for (int di = 0; di < 4; ++di) {
            int d = 16 * di + li, m0 = 64 * w + 16 * mi + 4 * g;
            *(float4*)&kvb[d * 256 + m0] =
                make_float4(acc[mi][di][0], acc[mi][di][1],
                            acc[mi][di][2], acc[mi][di][3]);
        }
}

// ------- K3: reduce partials -> kvT_sw bf16 [bh][80][256] (unchanged) ------
__global__ __launch_bounds__(256) void reduce_kv(const float* __restrict__ kvpart,
                                                 const float* __restrict__ kspart,
                                                 short* __restrict__ kvsT) {
    int bh = blockIdx.y, bx = blockIdx.x, t = threadIdx.x;
    if (bx < 4) {
#pragma unroll
        for (int i = 0; i < 16; ++i) {
            int idx = t + i * 256;               // 0..4095
            int d = 16 * bx + (idx >> 8), m = idx & 255;
            float s = 0.f;
            size_t base = ((size_t)(bh * 8) * 64 + d) * 256 + m;
#pragma unroll
            for (int c = 0; c < 8; ++c) s += kvpart[base + (size_t)c * 16384];
            int widx = (m & 128) + ((m & 127) ^ ((d & 7) << 3));
            kvsT[((size_t)bh * 80 + d) * 256 + widx] = f2bf(s);
        }
    } else {
        float s = 0.f;
#pragma unroll
        for (int c = 0; c < 8; ++c) s += kspart[((bh * 8 + c) << 8) + t];
        kvsT[((size_t)bh * 80 + 64) * 256 + t] = f2bf(s);
        for (int i = t; i < 15 * 256; i += 256) {
            int r = 65 + (i >> 8), cc = i & 255;
            kvsT[((size_t)bh * 80 + r) * 256 + cc] = 0;
        }
    }
}

// ------- K4: MFMA contract (unchanged) -------------------------------------
__global__ __launch_bounds__(256) void contract_mfma(
        const short* __restrict__ Qh,      // pre-swizzled, *DN
        const short* __restrict__ pjb,     // pre-swizzled bf16
        const short* __restrict__ kvsT,    // pre-swizzled bf16 [bh][80][256]
        short* __restrict__ attn) {
    int bh = blockIdx.y, rb = blockIdx.x, h = bh & 15, b = bh >> 4;
    int t = threadIdx.x, lane = t & 63, w = t >> 6;
    __shared__ __align__(16) short qs[64 * 64];    //  8KB [row][d]  (swz)
    __shared__ __align__(16) short pj[128 * 64];   // 16KB [m][d]    (swz)
    __shared__ __align__(16) short Pl[64 * 128];   // 16KB [row][m]  (swz)
    __shared__ __align__(16) short kvl[80 * 128];  // 20KB [d'][m]   (swz)

    {
        const short* src = Qh + ((size_t)bh * 4096 + rb * 64) * 64;
#pragma unroll
        for (int c2 = 0; c2 < 2; ++c2) {
            int c = 2 * w + c2;
            gload16(src + (c * 8 + (lane >> 3)) * 64 + (lane & 7) * 8,
                    qs + c * 512);
        }
    }

    f32x4 acc5[5];
#pragma unroll
    for (int i = 0; i < 5; ++i) acc5[i] = (f32x4){0.f, 0.f, 0.f, 0.f};

    int g = lane >> 4, li = lane & 15;

    for (int half = 0; half < 2; ++half) {
        __syncthreads();
        const short* psrc = pjb + (size_t)h * 16384 + half * 8192;
#pragma unroll
        for (int c2 = 0; c2 < 4; ++c2) {
            int c = 4 * w + c2;
            gload16(psrc + (c * 8 + (lane >> 3)) * 64 + (lane & 7) * 8,
                    pj + c * 512);
        }
        const short* ksrc = kvsT + (size_t)bh * 80 * 256 + half * 128;
#pragma unroll
        for (int c2 = 0; c2 < 5; ++c2) {
            int c = 5 * w + c2;
            gload16(ksrc + (c * 4 + (lane >> 4)) * 256 + (lane & 15) * 8,
                    kvl + c * 512);
        }
        __syncthreads();

        f32x4 sacc[2][4];
#pragma unroll
        for (int mi = 0; mi < 2; ++mi)
#pragma unroll
            for (int ni = 0; ni < 4; ++ni) sacc[mi][ni] = (f32x4){0.f, 0.f, 0.f, 0.f};
#pragma unroll
        for (int ks = 0; ks < 2; ++ks) {
            int kbyte = ks * 64 + g * 16;
            bf16x8 afr[2], bfr[4];
#pragma unroll
            for (int mi = 0; mi < 2; ++mi) {
                int mr = 32 * w + 16 * mi + li;
                afr[mi] = *(const bf16x8*)((const char*)pj +
                           mr * 128 + (kbyte ^ ((mr & 7) << 4)));
            }
#pragma unroll
            for (int ni = 0; ni < 4; ++ni) {
                int qr = 16 * ni + li;
                bfr[ni] = *(const bf16x8*)((const char*)qs +
                           qr * 128 + (kbyte ^ ((qr & 7) << 4)));
            }
#pragma unroll
            for (int mi = 0; mi < 2; ++mi)
#pragma unroll
                for (int ni = 0; ni < 4; ++ni)
                    sacc[mi][ni] = __builtin_amdgcn_mfma_f32_16x16x32_bf16(
                        afr[mi], bfr[ni], sacc[mi][ni], 0, 0, 0);
        }

#pragma unroll
        for (int mi = 0; mi < 2; ++mi) {
            int m0 = 32 * w + 16 * mi + 4 * g;
#pragma unroll
            for (int ni = 0; ni < 4; ++ni) {
                int row = 16 * ni + li;
                float e0 = (__expf(sacc[mi][ni][0]) + EPSF) * INV_SQRT_M;
                float e1 = (__expf(sacc[mi][ni][1]) + EPSF) * INV_SQRT_M;
                float e2 = (__expf(sacc[mi][ni][2]) + EPSF) * INV_SQRT_M;
                float e3 = (__expf(sacc[mi][ni][3]) + EPSF) * INV_SQRT_M;
                uint32_t u0 = (uint32_t)(uint16_t)f2bf(e0) |
                              ((uint32_t)(uint16_t)f2bf(e1) << 16);
                uint32_t u1 = (uint32_t)(uint16_t)f2bf(e2) |
                              ((uint32_t)(uint16_t)f2bf(e3) << 16);
                int byte = row * 256 + ((m0 * 2) ^ ((row & 7) << 4));
                *(uint2*)((char*)Pl + byte) = make_uint2(u0, u1);
            }
        }
        __syncthreads();

        int rowA = 16 * w + li;
        int abase = rowA * 256;
        int asw = (rowA & 7) << 4;
#pragma unroll
        for (int ks = 0; ks < 4; ++ks) {
            int kbyte = ks * 64 + g * 16;
            bf16x8 pa = *(const bf16x8*)((const char*)Pl + abase + (kbyte ^ asw));
#pragma unroll
            for (int ni = 0; ni < 5; ++ni) {
                int rowB = 16 * ni + li;
                bf16x8 bv = *(const bf16x8*)((const char*)kvl +
                             rowB * 256 + (kbyte ^ ((rowB & 7) << 4)));
                acc5[ni] = __builtin_amdgcn_mfma_f32_16x16x32_bf16(
                    pa, bv, acc5[ni], 0, 0, 0);
            }
        }
    }

    float dj[4];
#pragma unroll
    for (int jj = 0; jj < 4; ++jj)
        dj[jj] = __shfl(acc5[4][jj], lane & 48) + EPSF;
#pragma unroll
    for (int ni = 0; ni < 4; ++ni) {
        int d = 16 * ni + li;
#pragma unroll
        for (int jj = 0; jj < 4; ++jj) {
            int n = rb * 64 + 16 * w + 4 * g + jj;
            attn[((size_t)b * 4096 + n) * 1024 + h * 64 + d] =
                f2bf(acc5[ni][jj] / dj[jj]);
        }
    }
}

extern "C" void kernel_launch(void* const* d_in, const int* in_sizes, int n_in,
                              void* d_out, int out_size, void* d_ws, size_t ws_size,
                              hipStream_t stream) {
    const float* x      = (const float*)d_in[0];
    const float* w_qkv  = (const float*)d_in[1];
    const float* b_qkv  = (const float*)d_in[2];
    const float* w_out  = (const float*)d_in[3];
    const float* b_out  = (const float*)d_in[4];
    const float* proj   = (const float*)d_in[5];
    float* out = (float*)d_out;

    // workspace layout (bytes), total ~139.5 MiB
    char* w = (char*)d_ws;
    short* xb     = (short*)(w);                        // 32 MiB -> kvpart overlay
    short* wqT    = (short*)(w + 33554432);             // 6 MiB
    short* wOT    = (short*)(w + 39845888);             // 2 MiB
    short* Qh     = (short*)(w + 41943040);             // 32 MiB (swz, *DN)
    short* Kh     = (short*)(w + 75497472);             // 32 MiB (swz, *DN) -> attn
    short* Vt     = (short*)(w + 109051904);            // 32 MiB transposed n-swz
    float* kvpart = (float*)(w);                        // overlay (xb dead)
    float* kspart = (float*)(w + 142606336);            // 512 KiB
    short* kvsT   = (short*)(w + 143130624);            // 2.5 MiB [64][80][256]
    short* pjb    = (short*)(w + 145752064);            // 512 KiB
    short* attn   = Kh;                                 // overlay (Kh dead)

    conv_x<<<dim3(16384), 256, 0, stream>>>(x, xb);
    convt_w<<<dim3(48, 16), 256, 0, stream>>>(w_qkv, wqT, 1024, 3072);
    convt_w<<<dim3(16, 16), 256, 0, stream>>>(w_out, wOT, 1024, 1024);
    conv_proj<<<dim3(1024), 256, 0, stream>>>(proj, pjb);
    mfma_gemm_qkv<<<dim3(3072), 256, 0, stream>>>(xb, wqT, b_qkv, Qh, Kh, Vt);
    fmap_mfma<<<dim3(8, 64), 256, 0, stream>>>(Kh, Vt, pjb, kvpart, kspart);
    reduce_kv<<<dim3(5, 64), 256, 0, stream>>>(kvpart, kspart, kvsT);
    contract_mfma<<<dim3(64, 64), 256, 0, stream>>>(Qh, pjb, kvsT, attn);
    mfma_gemm_out<<<dim3(1024), 256, 0, stream>>>(attn, wOT, b_out, out);
}